// Round 2
// baseline (881.953 us; speedup 1.0000x reference)
//
#include <hip/hip_runtime.h>

// NPG model: E=4 ensembles, B=16384, STATE=29, ACT=8, HID=512.
// R4: revert to 256 blocks x 64 rows x 8 waves (1 block/CU, lockstep weight
// stream -> L2-resident weights, FETCH ~23MB). New: swapped-operand MFMAs
// (D = Wt_pack x Xt_pack; packed weights serve as A-operand unchanged).
// Lane then holds 4 CONSECUTIVE COLUMNS of one row -> all layer outputs
// stored as ds_write_b64 (8x fewer LDS writes, conflict-free w/ XOR swizzle).
// Leg layer2 (512->4) fused in registers (f32 w2 from LDS + shfl reduce +
// LDS atomics) -- no h2 staging, no idle-wave phases. Pose layer2 via MFMA
// on Y2 staged in h1's upper half. Barriers ~190 -> ~45 per block.

#define E_ 4
#define B_ 16384

typedef float f32x4 __attribute__((ext_vector_type(4)));
typedef __bf16 bf16x8 __attribute__((ext_vector_type(8)));
typedef __bf16 bf16x4 __attribute__((ext_vector_type(4)));

__device__ __forceinline__ f32x4 mfma16(bf16x8 a, bf16x8 b, f32x4 c) {
  return __builtin_amdgcn_mfma_f32_16x16x32_bf16(a, b, c, 0, 0, 0);
}

// XOR-swizzled LDS address: row stride 1024 B (512 bf16 cols), 16B-slot swizzle
__device__ __forceinline__ __bf16* swz(__bf16* base, int row, int col) {
  int byte = (row << 10) + (col << 1);
  byte ^= (row & 7) << 4;
  return (__bf16*)((char*)base + byte);
}

// leg-format position mapping: output slot 13+k <- leg-block ib, component j
__device__ __forceinline__ void fmt_map(int k, int& ib, int& j) {
  if (k < 8) { ib = k >> 1; j = (k & 1) ? 2 : 0; }
  else { int k8 = k - 8; ib = k8 >> 1; j = (k8 & 1) ? 3 : 1; }
}

// ---------------- prep: pack weights into bf16 MFMA-B-fragment order --------
// Packed W (K x N): tiles (nt,kt) of 32x16; element ((nt*KT+kt)*64+lane)*8+j
// holds W[kt*32 + (lane>>4)*8 + j][nt*16 + (lane&15)].  Used as the A-operand
// of the swapped MFMA: A[m][k] = W[k][m].
__device__ __forceinline__ void pack_one(int idx, int per_e, int KT, int Kreal,
                                         int Nsrc, int Nval,
                                         const float* __restrict__ src,
                                         const float* __restrict__ sigma,
                                         __bf16* __restrict__ dst)
{
  int e = idx / per_e;
  int rem = idx - e * per_e;
  int g = rem >> 9;            // nt*KT + kt
  int nt = g / KT;
  int kt = g - nt * KT;
  int li = rem & 511;
  int lane = li >> 3, j = li & 7;
  int k = kt * 32 + (lane >> 4) * 8 + j;
  int n = nt * 16 + (lane & 15);
  float v = 0.f;
  if (k < Kreal && n < Nval) {
    v = src[(size_t)e * Kreal * Nsrc + (size_t)k * Nsrc + n];
    if (sigma) v *= 1.f / (sigma[k] + 1e-8f);   // fold input normalization
  }
  dst[idx] = (__bf16)v;
}

__global__ void prep_kernel(const float* __restrict__ wl0, const float* __restrict__ wl1,
                            const float* __restrict__ wl2, const float* __restrict__ wp0,
                            const float* __restrict__ wp1, const float* __restrict__ wp2,
                            const float* __restrict__ bl0, const float* __restrict__ bp0,
                            const float* __restrict__ mu_leg, const float* __restrict__ sigma_leg,
                            const float* __restrict__ mu_pose, const float* __restrict__ sigma_pose,
                            __bf16* __restrict__ WL0p, __bf16* __restrict__ WL1p,
                            __bf16* __restrict__ WL2p, __bf16* __restrict__ WP0p,
                            __bf16* __restrict__ WP1p, __bf16* __restrict__ WP2p,
                            float* __restrict__ bl0f, float* __restrict__ bp0f)
{
  const int S0 = 65536, S1 = 1048576, S2 = 32768;
  const int total = 2 * (S0 + S1 + S2) + 4096;
  for (int idx0 = blockIdx.x * blockDim.x + threadIdx.x; idx0 < total;
       idx0 += gridDim.x * blockDim.x) {
    int x = idx0;
    if (x < S0)              { pack_one(x, 16384, 1, 6, 512, 512, wl0, sigma_leg, WL0p); }
    else if ((x -= S0) < S1) { pack_one(x, 262144, 16, 512, 512, 512, wl1, nullptr, WL1p); }
    else if ((x -= S1) < S2) { pack_one(x, 8192, 16, 512, 8, 8, wl2, nullptr, WL2p); }
    else if ((x -= S2) < S0) { pack_one(x, 16384, 1, 29, 512, 512, wp0, sigma_pose, WP0p); }
    else if ((x -= S0) < S1) { pack_one(x, 262144, 16, 512, 512, 512, wp1, nullptr, WP1p); }
    else if ((x -= S1) < S2) { pack_one(x, 8192, 16, 512, 26, 16, wp2, nullptr, WP2p); }
    else {
      x -= S2;  // bias folds: b0' = b0 - sum_k mu[k]/(sigma[k]+eps) * W0[k,:]
      if (x < 2048) {
        int e = x >> 9, n = x & 511;
        float s = bl0[e * 512 + n];
        #pragma unroll
        for (int k = 0; k < 6; ++k)
          s -= mu_leg[k] / (sigma_leg[k] + 1e-8f) * wl0[(e * 6 + k) * 512 + n];
        bl0f[e * 512 + n] = s;
      } else {
        x -= 2048;
        int e = x >> 9, n = x & 511;
        float s = bp0[e * 512 + n];
        for (int k = 0; k < 29; ++k)
          s -= mu_pose[k] / (sigma_pose[k] + 1e-8f) * wp0[(e * 29 + k) * 512 + n];
        bp0f[e * 512 + n] = s;
      }
    }
  }
}

// ---------------- fused model kernel ----------------------------------------
__global__ __launch_bounds__(512, 2) void fused_kernel(
    const float* __restrict__ state, const float* __restrict__ act,
    const float* __restrict__ wl2,
    const float* __restrict__ bl1, const float* __restrict__ bl2,
    const float* __restrict__ bp1, const float* __restrict__ bp2,
    const float* __restrict__ mu_t_leg, const float* __restrict__ sigma_t_leg,
    const float* __restrict__ mu_t_pose, const float* __restrict__ sigma_t_pose,
    const __bf16* __restrict__ WL0p, const __bf16* __restrict__ WL1p,
    const __bf16* __restrict__ WP0p, const __bf16* __restrict__ WP1p,
    const __bf16* __restrict__ WP2p,
    const float* __restrict__ bl0f, const float* __restrict__ bp0f,
    float* __restrict__ out)
{
  __shared__ alignas(16) __bf16 h1[128 * 512];   // 131072 B (leg Y1 / pose Y1+Y2)
  __shared__ alignas(16) __bf16 a0s[128 * 40];   // 10240 B
  __shared__ float ldiffr[64][16];               // 4096 B (raw leg-L2 sums)
  __shared__ alignas(16) float w2l[512][4];      // 8192 B (leg W2, f32)
  __shared__ alignas(16) float pored[64][16];    // 4096 B -> total 157696 B
  __bf16* Y2p = h1 + 64 * 512;                   // pose Y2 in h1's upper half

  const int tid = threadIdx.x;
  const int wv = tid >> 6;        // wave 0..7
  const int lane = tid & 63;
  const int quad = lane >> 4;
  const int l16 = lane & 15;
  const int b0 = blockIdx.x * 64;

  const int lt = tid >> 3;        // legacc owner row 0..63
  const int lk = tid & 7;
  float legacc0 = 0.f, legacc1 = 0.f;
  f32x4 posacc = {0.f, 0.f, 0.f, 0.f};

  for (int e = 0; e < E_; ++e) {
    const float* se = state + (size_t)e * B_ * 29;
    const float* ae = act + (size_t)e * B_ * 8;

    // ================= leg MLP: 2 halves of 32 batch rows (128 leg rows) ====
    for (int h = 0; h < 2; ++h) {
      __syncthreads();
      if (h == 0) {   // per-e init: zero leg-L2 accum, stage leg W2 (f32)
        ((float*)ldiffr)[tid] = 0.f;
        ((float*)ldiffr)[tid + 512] = 0.f;
        *(f32x4*)&w2l[tid][0] = *(const f32x4*)(wl2 + (size_t)e * 4096 + tid * 8);
      }
      // ---- a0 build: 128 leg rows (ib*32+t) x 32 cols (6 real)
      for (int i = tid; i < 128 * 32; i += 512) {
        int r = i >> 5, c = i & 31;
        int ib = r >> 5, t = r & 31;
        int b = b0 + h * 32 + t;
        const float* sp = se + (size_t)b * 29;
        float v = 0.f;
        if (c == 0) v = sp[13 + 2 * ib];
        else if (c == 1) v = sp[21 + 2 * ib];
        else if (c == 2) v = sp[14 + 2 * ib];
        else if (c == 3) v = sp[22 + 2 * ib];
        else if (c == 4) v = ae[(size_t)b * 8 + 2 * ib];
        else if (c == 5) v = ae[(size_t)b * 8 + 2 * ib + 1];
        a0s[r * 40 + c] = (__bf16)v;
      }
      __syncthreads();

      // ---- L0 (swapped): h1[row][col] = relu(a0 @ W0 + b0'); wave: 64 cols
      {
        const __bf16* W0 = WL0p + (size_t)e * 16384;
        const float* b0v = bl0f + e * 512;
        bf16x8 wfr[4]; f32x4 bias[4];
        #pragma unroll
        for (int i = 0; i < 4; ++i) {
          int nt = wv * 4 + i;
          wfr[i] = *(const bf16x8*)(W0 + ((size_t)nt * 64 + lane) * 8);
          int cb = nt * 16 + quad * 4;
          bias[i] = (f32x4){b0v[cb], b0v[cb + 1], b0v[cb + 2], b0v[cb + 3]};
        }
        for (int rt = 0; rt < 8; ++rt) {
          bf16x8 xfr = *(const bf16x8*)&a0s[(rt * 16 + l16) * 40 + quad * 8];
          #pragma unroll
          for (int i = 0; i < 4; ++i) {
            f32x4 acc = mfma16(wfr[i], xfr, bias[i]);
            bf16x4 pk;
            #pragma unroll
            for (int r = 0; r < 4; ++r) pk[r] = (__bf16)fmaxf(acc[r], 0.f);
            *(bf16x4*)swz(h1, rt * 16 + l16, (wv * 4 + i) * 16 + quad * 4) = pk;
          }
        }
      }
      __syncthreads();

      // ---- L1 (128x512x512) + register-fused L2 (512->4)
      {
        const __bf16* W1 = WL1p + (size_t)e * 262144;
        const float* b1v = bl1 + e * 512;
        const int rg = wv >> 2, cg = wv & 3;   // rows rg*64, cols cg*64 (+cc*256)
        f32x4 partial[4];
        #pragma unroll
        for (int i = 0; i < 4; ++i) partial[i] = (f32x4){0.f, 0.f, 0.f, 0.f};

        for (int cc = 0; cc < 2; ++cc) {
          f32x4 acc[4][4];
          #pragma unroll
          for (int ctw = 0; ctw < 4; ++ctw) {
            int cb = cc * 256 + cg * 64 + ctw * 16 + quad * 4;
            f32x4 b = (f32x4){b1v[cb], b1v[cb + 1], b1v[cb + 2], b1v[cb + 3]};
            #pragma unroll
            for (int i = 0; i < 4; ++i) acc[i][ctw] = b;
          }
          #pragma unroll 4
          for (int kt = 0; kt < 16; ++kt) {
            bf16x8 yfr[4];
            #pragma unroll
            for (int i = 0; i < 4; ++i)
              yfr[i] = *(const bf16x8*)swz(h1, rg * 64 + i * 16 + l16,
                                           kt * 32 + quad * 8);
            #pragma unroll
            for (int ctw = 0; ctw < 4; ++ctw) {
              int nt = cc * 16 + cg * 4 + ctw;
              bf16x8 wfr = *(const bf16x8*)(W1 + (((size_t)nt * 16 + kt) * 64 + lane) * 8);
              #pragma unroll
              for (int i = 0; i < 4; ++i) acc[i][ctw] = mfma16(wfr, yfr[i], acc[i][ctw]);
            }
          }
          // fused L2: partial[i][o] += relu(y) * w2[col][o]
          #pragma unroll
          for (int ctw = 0; ctw < 4; ++ctw) {
            #pragma unroll
            for (int r = 0; r < 4; ++r) {
              int col = cc * 256 + cg * 64 + ctw * 16 + quad * 4 + r;
              f32x4 w = *(const f32x4*)&w2l[col][0];
              #pragma unroll
              for (int i = 0; i < 4; ++i)
                partial[i] += w * fmaxf(acc[i][ctw][r], 0.f);
            }
          }
        }
        // quad-reduce + accumulate into ldiffr
        #pragma unroll
        for (int i = 0; i < 4; ++i) {
          f32x4 p = partial[i];
          #pragma unroll
          for (int c = 0; c < 4; ++c) {
            p[c] += __shfl_xor(p[c], 16);
            p[c] += __shfl_xor(p[c], 32);
          }
          if (quad == 0) {
            int rleg = rg * 64 + i * 16 + l16;
            int ib = rleg >> 5, t = rleg & 31;
            #pragma unroll
            for (int o = 0; o < 4; ++o)
              atomicAdd(&ldiffr[h * 32 + t][ib * 4 + o], p[o]);
          }
        }
      }
    } // h

    // ================= pose MLP: 64 rows =================
    __syncthreads();   // ldiffr complete; a0s free
    for (int i = tid; i < 64 * 32; i += 512) {
      int t = i >> 5, c = i & 31;
      float v = 0.f;
      if (c < 13) v = se[(size_t)(b0 + t) * 29 + c];
      else if (c < 29) {
        int ib, j; fmt_map(c - 13, ib, j);
        v = (ldiffr[t][ib * 4 + j] + bl2[e * 8 + j]) * (sigma_t_leg[j] + 1e-8f)
            + mu_t_leg[j];
      }
      a0s[t * 40 + c] = (__bf16)v;
    }
    {   // legs output accumulation (registers)
      int ib0, j0, ib1, j1;
      fmt_map(lk, ib0, j0); fmt_map(lk + 8, ib1, j1);
      float d0 = (ldiffr[lt][ib0 * 4 + j0] + bl2[e * 8 + j0]) * (sigma_t_leg[j0] + 1e-8f) + mu_t_leg[j0];
      float d1 = (ldiffr[lt][ib1 * 4 + j1] + bl2[e * 8 + j1]) * (sigma_t_leg[j1] + 1e-8f) + mu_t_leg[j1];
      legacc0 += se[(size_t)(b0 + lt) * 29 + 13 + lk] + d0;
      legacc1 += se[(size_t)(b0 + lt) * 29 + 21 + lk] + d1;
    }
    __syncthreads();

    // ---- pose L0: h1 rows 0..63
    {
      const __bf16* W0 = WP0p + (size_t)e * 16384;
      const float* b0v = bp0f + e * 512;
      bf16x8 wfr[4]; f32x4 bias[4];
      #pragma unroll
      for (int i = 0; i < 4; ++i) {
        int nt = wv * 4 + i;
        wfr[i] = *(const bf16x8*)(W0 + ((size_t)nt * 64 + lane) * 8);
        int cb = nt * 16 + quad * 4;
        bias[i] = (f32x4){b0v[cb], b0v[cb + 1], b0v[cb + 2], b0v[cb + 3]};
      }
      for (int rt = 0; rt < 4; ++rt) {
        bf16x8 xfr = *(const bf16x8*)&a0s[(rt * 16 + l16) * 40 + quad * 8];
        #pragma unroll
        for (int i = 0; i < 4; ++i) {
          f32x4 acc = mfma16(wfr[i], xfr, bias[i]);
          bf16x4 pk;
          #pragma unroll
          for (int r = 0; r < 4; ++r) pk[r] = (__bf16)fmaxf(acc[r], 0.f);
          *(bf16x4*)swz(h1, rt * 16 + l16, (wv * 4 + i) * 16 + quad * 4) = pk;
        }
      }
    }
    __syncthreads();

    // ---- pose L1 (64x512x512) -> Y2p (b64 swizzled stores)
    {
      const __bf16* W1 = WP1p + (size_t)e * 262144;
      const float* b1v = bp1 + e * 512;
      f32x4 acc[4][4];
      #pragma unroll
      for (int ctw = 0; ctw < 4; ++ctw) {
        int cb = wv * 64 + ctw * 16 + quad * 4;
        f32x4 b = (f32x4){b1v[cb], b1v[cb + 1], b1v[cb + 2], b1v[cb + 3]};
        #pragma unroll
        for (int i = 0; i < 4; ++i) acc[i][ctw] = b;
      }
      #pragma unroll 4
      for (int kt = 0; kt < 16; ++kt) {
        bf16x8 yfr[4];
        #pragma unroll
        for (int i = 0; i < 4; ++i)
          yfr[i] = *(const bf16x8*)swz(h1, i * 16 + l16, kt * 32 + quad * 8);
        #pragma unroll
        for (int ctw = 0; ctw < 4; ++ctw) {
          int nt = wv * 4 + ctw;
          bf16x8 wfr = *(const bf16x8*)(W1 + (((size_t)nt * 16 + kt) * 64 + lane) * 8);
          #pragma unroll
          for (int i = 0; i < 4; ++i) acc[i][ctw] = mfma16(wfr, yfr[i], acc[i][ctw]);
        }
      }
      #pragma unroll
      for (int i = 0; i < 4; ++i)
        #pragma unroll
        for (int ctw = 0; ctw < 4; ++ctw) {
          bf16x4 pk;
          #pragma unroll
          for (int r = 0; r < 4; ++r) pk[r] = (__bf16)fmaxf(acc[i][ctw][r], 0.f);
          *(bf16x4*)swz(Y2p, i * 16 + l16, wv * 64 + ctw * 16 + quad * 4) = pk;
        }
    }
    __syncthreads();

    // ---- pose L2 (64x512x16): wave = (row-tile rt, k-half kh)
    {
      const __bf16* W2 = WP2p + (size_t)e * 8192;
      const int rt = wv >> 1, kh = wv & 1;
      f32x4 po;
      if (kh == 0) {
        int m0 = quad * 4;
        po = (f32x4){bp2[e * 26 + m0], bp2[e * 26 + m0 + 1],
                     bp2[e * 26 + m0 + 2], bp2[e * 26 + m0 + 3]};
      } else po = (f32x4){0.f, 0.f, 0.f, 0.f};
      #pragma unroll
      for (int k8 = 0; k8 < 8; ++k8) {
        int ks = kh * 8 + k8;
        bf16x8 yfr = *(const bf16x8*)swz(Y2p, rt * 16 + l16, ks * 32 + quad * 8);
        bf16x8 wfr = *(const bf16x8*)(W2 + ((size_t)ks * 64 + lane) * 8);
        po = mfma16(wfr, yfr, po);
      }
      if (kh == 1) *(f32x4*)&pored[rt * 16 + l16][quad * 4] = po;
      __syncthreads();
      if (kh == 0) {
        f32x4 pr = *(const f32x4*)&pored[rt * 16 + l16][quad * 4];
        #pragma unroll
        for (int r = 0; r < 4; ++r) {
          int m = quad * 4 + r;
          if (m < 13)
            posacc[r] += (po[r] + pr[r]) * (sigma_t_pose[m] + 1e-8f) + mu_t_pose[m]
                         + se[(size_t)(b0 + rt * 16 + l16) * 29 + m];
        }
      }
    }
  } // e

  // ================= final writes: mean over ensembles =================
  if ((wv & 1) == 0) {
    int row = (wv >> 1) * 16 + l16;
    #pragma unroll
    for (int r = 0; r < 4; ++r) {
      int m = quad * 4 + r;
      if (m < 13) out[(size_t)(b0 + row) * 29 + m] = 0.25f * posacc[r];
    }
  }
  out[(size_t)(b0 + lt) * 29 + 13 + lk] = 0.25f * legacc0;
  out[(size_t)(b0 + lt) * 29 + 21 + lk] = 0.25f * legacc1;
}

// ---------------- launch ----------------------------------------------------
extern "C" void kernel_launch(void* const* d_in, const int* in_sizes, int n_in,
                              void* d_out, int out_size, void* d_ws, size_t ws_size,
                              hipStream_t stream) {
  const float* state = (const float*)d_in[0];
  const float* act = (const float*)d_in[1];
  const float* wl0 = (const float*)d_in[2];
  const float* bl0 = (const float*)d_in[3];
  const float* wl1 = (const float*)d_in[4];
  const float* bl1 = (const float*)d_in[5];
  const float* wl2 = (const float*)d_in[6];
  const float* bl2 = (const float*)d_in[7];
  const float* wp0 = (const float*)d_in[8];
  const float* bp0 = (const float*)d_in[9];
  const float* wp1 = (const float*)d_in[10];
  const float* bp1 = (const float*)d_in[11];
  const float* wp2 = (const float*)d_in[12];
  const float* bp2 = (const float*)d_in[13];
  const float* mu_leg = (const float*)d_in[14];
  const float* sigma_leg = (const float*)d_in[15];
  const float* mu_pose = (const float*)d_in[16];
  const float* sigma_pose = (const float*)d_in[17];
  const float* mu_t_leg = (const float*)d_in[18];
  const float* sigma_t_leg = (const float*)d_in[19];
  const float* mu_t_pose = (const float*)d_in[20];
  const float* sigma_t_pose = (const float*)d_in[21];
  float* out = (float*)d_out;

  char* ws = (char*)d_ws;
  __bf16* WL0p = (__bf16*)(ws);
  __bf16* WL1p = (__bf16*)(ws + 131072);
  __bf16* WL2p = (__bf16*)(ws + 2228224);
  __bf16* WP0p = (__bf16*)(ws + 2293760);
  __bf16* WP1p = (__bf16*)(ws + 2424832);
  __bf16* WP2p = (__bf16*)(ws + 4521984);
  float* bl0f = (float*)(ws + 4587520);
  float* bp0f = (float*)(ws + 4595712);

  prep_kernel<<<512, 256, 0, stream>>>(wl0, wl1, wl2, wp0, wp1, wp2, bl0, bp0,
                                       mu_leg, sigma_leg, mu_pose, sigma_pose,
                                       WL0p, WL1p, WL2p, WP0p, WP1p, WP2p,
                                       bl0f, bp0f);
  fused_kernel<<<256, 512, 0, stream>>>(state, act, wl2, bl1, bl2, bp1, bp2,
                                        mu_t_leg, sigma_t_leg, mu_t_pose, sigma_t_pose,
                                        WL0p, WL1p, WP0p, WP1p, WP2p,
                                        bl0f, bp0f, out);
}

// Round 3
// 587.959 us; speedup vs baseline: 1.5000x; 1.5000x over previous
//
#include <hip/hip_runtime.h>

// NPG model: E=4 ensembles, B=16384, STATE=29, ACT=8, HID=512.
// R5 = exact R2 structure (256 blocks x 64 rows x 8 waves, 1 block/CU,
// lockstep weight stream) + two surgical changes:
//  (a) h1/h2c: padded strides (520/136) -> linear 512/128 + XOR swizzle
//      byte ^= (row&7)<<4 on BOTH write and read sides (G4/T2 recipe).
//      Targets the 2.3e7 SQ_LDS_BANK_CONFLICT (~13% of cycles) on the
//      b128 A-frag reads. Write-side conflict profile unchanged (2-way).
//  (b) prep split: coalesced strip-packer for the two 512x512 W1 matrices
//      (87% of prep work; was ~90us of gather at 2KB/lane stride);
//      small matrices/bias keep the old gather path.

#define E_ 4
#define B_ 16384
#define A0S 40    // a0 row stride (unswizzled, aliases h2c)

typedef float f32x4 __attribute__((ext_vector_type(4)));
typedef __bf16 bf16x8 __attribute__((ext_vector_type(8)));

__device__ __forceinline__ f32x4 mfma16(bf16x8 a, bf16x8 b, f32x4 c) {
  return __builtin_amdgcn_mfma_f32_16x16x32_bf16(a, b, c, 0, 0, 0);
}

// XOR-swizzled h1 address: 512 bf16 cols (1024B rows), 16B-slot swizzle.
__device__ __forceinline__ __bf16* swzh1(__bf16* base, int row, int col) {
  int byte = (row << 10) + (col << 1);
  byte ^= (row & 7) << 4;
  return (__bf16*)((char*)base + byte);
}
// XOR-swizzled h2c address: 128 bf16 cols (256B rows).
__device__ __forceinline__ __bf16* swzh2(__bf16* base, int row, int col) {
  int byte = (row << 8) + (col << 1);
  byte ^= (row & 7) << 4;
  return (__bf16*)((char*)base + byte);
}

// leg-format position mapping: output slot 13+k <- leg-block ib, component j
__device__ __forceinline__ void fmt_map(int k, int& ib, int& j) {
  if (k < 8) { ib = k >> 1; j = (k & 1) ? 2 : 0; }
  else { int k8 = k - 8; ib = k8 >> 1; j = (k8 & 1) ? 3 : 1; }
}

// ---------------- prep: pack weights into bf16 MFMA-B-fragment order --------
// Packed W (K x N): tiles (nt,kt) of 32x16; element ((nt*KT+kt)*64+lane)*8+j
// holds W[kt*32 + (lane>>4)*8 + j][nt*16 + (lane&15)]
__device__ __forceinline__ void pack_one(int idx, int per_e, int KT, int Kreal,
                                         int Nsrc, int Nval,
                                         const float* __restrict__ src,
                                         const float* __restrict__ sigma,
                                         __bf16* __restrict__ dst)
{
  int e = idx / per_e;
  int rem = idx - e * per_e;
  int g = rem >> 9;            // nt*KT + kt
  int nt = g / KT;
  int kt = g - nt * KT;
  int li = rem & 511;
  int lane = li >> 3, j = li & 7;
  int k = kt * 32 + (lane >> 4) * 8 + j;
  int n = nt * 16 + (lane & 15);
  float v = 0.f;
  if (k < Kreal && n < Nval) {
    v = src[(size_t)e * Kreal * Nsrc + (size_t)k * Nsrc + n];
    if (sigma) v *= 1.f / (sigma[k] + 1e-8f);   // fold input normalization
  }
  dst[idx] = (__bf16)v;
}

// Small matrices (W0 x2, W2 x2) + bias folds: old gather path (cheap, cached).
__global__ void prep_small(const float* __restrict__ wl0, const float* __restrict__ wl2,
                           const float* __restrict__ wp0, const float* __restrict__ wp2,
                           const float* __restrict__ bl0, const float* __restrict__ bp0,
                           const float* __restrict__ mu_leg, const float* __restrict__ sigma_leg,
                           const float* __restrict__ mu_pose, const float* __restrict__ sigma_pose,
                           __bf16* __restrict__ WL0p, __bf16* __restrict__ WL2p,
                           __bf16* __restrict__ WP0p, __bf16* __restrict__ WP2p,
                           float* __restrict__ bl0f, float* __restrict__ bp0f)
{
  const int S0 = 65536, S2 = 32768;
  const int total = 2 * (S0 + S2) + 4096;
  for (int idx0 = blockIdx.x * blockDim.x + threadIdx.x; idx0 < total;
       idx0 += gridDim.x * blockDim.x) {
    int x = idx0;
    if (x < S0)              { pack_one(x, 16384, 1, 6, 512, 512, wl0, sigma_leg, WL0p); }
    else if ((x -= S0) < S2) { pack_one(x, 8192, 16, 512, 8, 8, wl2, nullptr, WL2p); }
    else if ((x -= S2) < S0) { pack_one(x, 16384, 1, 29, 512, 512, wp0, sigma_pose, WP0p); }
    else if ((x -= S0) < S2) { pack_one(x, 8192, 16, 512, 26, 16, wp2, nullptr, WP2p); }
    else {
      x -= S2;  // bias folds: b0' = b0 - sum_k mu[k]/(sigma[k]+eps) * W0[k,:]
      if (x < 2048) {
        int e = x >> 9, n = x & 511;
        float s = bl0[e * 512 + n];
        #pragma unroll
        for (int k = 0; k < 6; ++k)
          s -= mu_leg[k] / (sigma_leg[k] + 1e-8f) * wl0[(e * 6 + k) * 512 + n];
        bl0f[e * 512 + n] = s;
      } else {
        x -= 2048;
        int e = x >> 9, n = x & 511;
        float s = bp0[e * 512 + n];
        for (int k = 0; k < 29; ++k)
          s -= mu_pose[k] / (sigma_pose[k] + 1e-8f) * wp0[(e * 29 + k) * 512 + n];
        bp0f[e * 512 + n] = s;
      }
    }
  }
}

// W1 matrices (512x512, no sigma, no padding): coalesced strip packer.
// Block = one (matrix, e, nt) 512x16 column strip. Stage f32->bf16 in LDS
// coalesced (16 f32 = 64B per row), emit packed strip as contiguous 16B
// stores (strip is contiguous in dst: offsets [nt*8192, nt*8192+8192)).
__global__ __launch_bounds__(256) void prep_w1(const float* __restrict__ wl1,
                                               const float* __restrict__ wp1,
                                               __bf16* __restrict__ WL1p,
                                               __bf16* __restrict__ WP1p)
{
  __shared__ __bf16 st[512][20];     // 20-col pad (40B rows) vs bank conflicts
  const int b = blockIdx.x;          // 0..255: [mat(1) | e(2) | nt(5)]
  const float* src = (b & 128) ? wp1 : wl1;
  __bf16* dst = (b & 128) ? WP1p : WL1p;
  const int e = (b >> 5) & 3, nt = b & 31;
  src += (size_t)e * 262144 + nt * 16;
  dst += (size_t)e * 262144 + (size_t)nt * 8192;
  const int t = threadIdx.x;

  const int k0 = t >> 2, nq = t & 3;
  #pragma unroll
  for (int it = 0; it < 8; ++it) {
    int k = it * 64 + k0;
    f32x4 v = *(const f32x4*)(src + (size_t)k * 512 + nq * 4);
    #pragma unroll
    for (int j = 0; j < 4; ++j) st[k][nq * 4 + j] = (__bf16)v[j];
  }
  __syncthreads();
  #pragma unroll
  for (int it = 0; it < 4; ++it) {
    int lo = it * 256 + t;           // bf16x8 index 0..1023
    int kt = lo >> 6, lane = lo & 63;
    int kb = kt * 32 + (lane >> 4) * 8;
    int n = lane & 15;
    bf16x8 o;
    #pragma unroll
    for (int j = 0; j < 8; ++j) o[j] = st[kb + j][n];
    *(bf16x8*)(dst + (size_t)lo * 8) = o;
  }
}

// ---------------- fused model kernel (R2 structure + XOR swizzle) -----------
__global__ __launch_bounds__(512) void fused_kernel(
    const float* __restrict__ state, const float* __restrict__ act,
    const float* __restrict__ bl1, const float* __restrict__ bl2,
    const float* __restrict__ bp1, const float* __restrict__ bp2,
    const float* __restrict__ mu_t_leg, const float* __restrict__ sigma_t_leg,
    const float* __restrict__ mu_t_pose, const float* __restrict__ sigma_t_pose,
    const __bf16* __restrict__ WL0p, const __bf16* __restrict__ WL1p,
    const __bf16* __restrict__ WL2p, const __bf16* __restrict__ WP0p,
    const __bf16* __restrict__ WP1p, const __bf16* __restrict__ WP2p,
    const float* __restrict__ bl0f, const float* __restrict__ bp0f,
    float* __restrict__ out)
{
  __shared__ alignas(16) __bf16 h1[128 * 512];   // 131072 B, XOR-swizzled
  __shared__ alignas(16) __bf16 h2c[64 * 128];   // 16384 B, XOR-swizzled (a0 alias)
  __shared__ float ldiff[64][16];                // 4096 B
  __shared__ float legacc[64][16];               // 4096 B  -> total 155648 B
  __bf16* a0s = h2c;                             // a0 = 128*40 elems, fits

  const int tid = threadIdx.x;
  const int wv = tid >> 6;        // wave 0..7
  const int lane = tid & 63;
  const int quad = lane >> 4;
  const int l16 = lane & 15;
  const int b0 = blockIdx.x * 64;

  for (int i = tid; i < 64 * 16; i += 512) ((float*)legacc)[i] = 0.f;
  f32x4 posacc = {0.f, 0.f, 0.f, 0.f};
  __syncthreads();

  for (int e = 0; e < E_; ++e) {
    const float* se = state + (size_t)e * B_ * 29;
    const float* ae = act + (size_t)e * B_ * 8;

    // ================= leg MLP: 2 passes of 128 leg rows =================
    for (int half = 0; half < 2; ++half) {
      __syncthreads();   // h2c/a0 region free (prior readers done)
      // ---- a0 build: 128 rows (ib*32+t) x 32 cols (6 real)
      for (int i = tid; i < 128 * 32; i += 512) {
        int r = i >> 5, c = i & 31;
        float v = 0.f;
        if (c < 6) {
          int ib = r >> 5;
          int b = b0 + half * 32 + (r & 31);
          const float* sp = se + (size_t)b * 29;
          if (c == 0) v = sp[13 + 2 * ib];
          else if (c == 1) v = sp[21 + 2 * ib];
          else if (c == 2) v = sp[14 + 2 * ib];
          else if (c == 3) v = sp[22 + 2 * ib];
          else if (c == 4) v = ae[(size_t)b * 8 + 2 * ib];
          else v = ae[(size_t)b * 8 + 2 * ib + 1];
        }
        a0s[r * A0S + c] = (__bf16)v;
      }
      __syncthreads();

      // ---- layer0: h1(128x512) = relu(A0 @ W0 + b0'); wave owns 4 col-tiles
      {
        const __bf16* W0 = WL0p + (size_t)e * 16384;
        const float* b0v = bl0f + e * 512;
        bf16x8 bfr[4]; float bs[4];
        #pragma unroll
        for (int i = 0; i < 4; ++i) {
          int ct = wv * 4 + i;
          bfr[i] = *(const bf16x8*)(W0 + ((size_t)ct * 64 + lane) * 8);
          bs[i] = b0v[ct * 16 + l16];
        }
        for (int rt = 0; rt < 8; ++rt) {
          bf16x8 afr = *(const bf16x8*)&a0s[(rt * 16 + l16) * A0S + quad * 8];
          #pragma unroll
          for (int i = 0; i < 4; ++i) {
            f32x4 acc = {bs[i], bs[i], bs[i], bs[i]};
            acc = mfma16(afr, bfr[i], acc);
            int col = (wv * 4 + i) * 16 + l16;
            #pragma unroll
            for (int r = 0; r < 4; ++r)
              *swzh1(h1, rt * 16 + quad * 4 + r, col) = (__bf16)fmaxf(acc[r], 0.f);
          }
        }
      }
      __syncthreads();

      // ---- layer1 (128x512x512) + fused layer2; wave tile 64r x 32c
      const __bf16* W1 = WL1p + (size_t)e * 262144;
      const __bf16* W2 = WL2p + (size_t)e * 8192;
      const float* b1v = bl1 + e * 512;
      const int rg = wv >> 2, cg = wv & 3;
      float bv2 = (l16 < 8) ? bl2[e * 8 + l16] : 0.f;
      f32x4 oacc = {bv2, bv2, bv2, bv2};     // wave wv owns row-tile wv (l2)

      for (int cc = 0; cc < 4; ++cc) {
        f32x4 acc[4][2];
        #pragma unroll
        for (int ct = 0; ct < 2; ++ct) {
          float bias = b1v[cc * 128 + cg * 32 + ct * 16 + l16];
          #pragma unroll
          for (int i = 0; i < 4; ++i) acc[i][ct] = (f32x4){bias, bias, bias, bias};
        }
        const __bf16* Wc = W1 + (size_t)(cc * 8 + cg * 2) * 8192;
        #pragma unroll 4
        for (int kt = 0; kt < 16; ++kt) {
          bf16x8 afr[4];
          #pragma unroll
          for (int i = 0; i < 4; ++i)
            afr[i] = *(const bf16x8*)swzh1(h1, rg * 64 + i * 16 + l16,
                                           kt * 32 + quad * 8);
          #pragma unroll
          for (int ct = 0; ct < 2; ++ct) {
            bf16x8 bfr = *(const bf16x8*)(Wc + (((size_t)ct * 16 + kt) * 64 + lane) * 8);
            #pragma unroll
            for (int i = 0; i < 4; ++i) acc[i][ct] = mfma16(afr[i], bfr, acc[i][ct]);
          }
        }
        // stage h2 in two 64-row halves; owners accumulate layer2
        #pragma unroll
        for (int hh = 0; hh < 2; ++hh) {
          __syncthreads();
          if (rg == hh) {
            #pragma unroll
            for (int i = 0; i < 4; ++i)
              #pragma unroll
              for (int ct = 0; ct < 2; ++ct)
                #pragma unroll
                for (int r = 0; r < 4; ++r)
                  *swzh2(h2c, i * 16 + quad * 4 + r, cg * 32 + ct * 16 + l16) =
                      (__bf16)fmaxf(acc[i][ct][r], 0.f);
          }
          __syncthreads();
          if ((wv >> 2) == hh) {
            #pragma unroll
            for (int k2 = 0; k2 < 4; ++k2) {
              bf16x8 afr2 = *(const bf16x8*)swzh2(h2c, (wv & 3) * 16 + l16,
                                                  k2 * 32 + quad * 8);
              bf16x8 bfr2 = *(const bf16x8*)(W2 + ((size_t)(cc * 4 + k2) * 64 + lane) * 8);
              oacc = mfma16(afr2, bfr2, oacc);
            }
          }
        }
      }
      // ---- leg epilogue: ldiff (only first 4 outputs used)
      if (l16 < 4) {
        float sc = sigma_t_leg[l16] + 1e-8f;
        float mv = mu_t_leg[l16];
        #pragma unroll
        for (int r = 0; r < 4; ++r) {
          int L = wv * 16 + quad * 4 + r;    // leg row = ib*32 + t
          ldiff[half * 32 + (L & 31)][(L >> 5) * 4 + l16] = oacc[r] * sc + mv;
        }
      }
    } // half

    // ================= pose MLP: 64 rows =================
    __syncthreads();   // ldiff ready, h2c free
    for (int i = tid; i < 64 * 32; i += 512) {
      int t = i >> 5, c = i & 31;
      float v = 0.f;
      if (c < 13) v = se[(size_t)(b0 + t) * 29 + c];
      else if (c < 29) { int ib, j; fmt_map(c - 13, ib, j); v = ldiff[t][ib * 4 + j]; }
      a0s[t * A0S + c] = (__bf16)v;
    }
    for (int i = tid; i < 64 * 16; i += 512) {   // legs output accumulation
      int t = i >> 4, k = i & 15;
      int ib, j; fmt_map(k, ib, j);
      legacc[t][k] += se[(size_t)(b0 + t) * 29 + 13 + k] + ldiff[t][ib * 4 + j];
    }
    __syncthreads();

    // ---- pose layer0: h1(64x512)
    {
      const __bf16* W0 = WP0p + (size_t)e * 16384;
      const float* b0v = bp0f + e * 512;
      bf16x8 bfr[4]; float bs[4];
      #pragma unroll
      for (int i = 0; i < 4; ++i) {
        int ct = wv * 4 + i;
        bfr[i] = *(const bf16x8*)(W0 + ((size_t)ct * 64 + lane) * 8);
        bs[i] = b0v[ct * 16 + l16];
      }
      for (int rt = 0; rt < 4; ++rt) {
        bf16x8 afr = *(const bf16x8*)&a0s[(rt * 16 + l16) * A0S + quad * 8];
        #pragma unroll
        for (int i = 0; i < 4; ++i) {
          f32x4 acc = {bs[i], bs[i], bs[i], bs[i]};
          acc = mfma16(afr, bfr[i], acc);
          int col = (wv * 4 + i) * 16 + l16;
          #pragma unroll
          for (int r = 0; r < 4; ++r)
            *swzh1(h1, rt * 16 + quad * 4 + r, col) = (__bf16)fmaxf(acc[r], 0.f);
        }
      }
    }
    __syncthreads();

    // ---- pose layer1 (64x512x512) + fused layer2 (N=13 -> 1 col-tile)
    {
      const __bf16* W1 = WP1p + (size_t)e * 262144;
      const __bf16* W2 = WP2p + (size_t)e * 8192;
      const float* b1v = bp1 + e * 512;
      float bvp = bp2[e * 26 + l16];
      f32x4 po = {bvp, bvp, bvp, bvp};       // waves 0..3 own row-tiles 0..3

      for (int cc2 = 0; cc2 < 2; ++cc2) {
        f32x4 acc[4][2];
        #pragma unroll
        for (int ct = 0; ct < 2; ++ct) {
          float bias = b1v[cc2 * 256 + wv * 32 + ct * 16 + l16];
          #pragma unroll
          for (int i = 0; i < 4; ++i) acc[i][ct] = (f32x4){bias, bias, bias, bias};
        }
        const __bf16* Wc = W1 + (size_t)(cc2 * 16 + wv * 2) * 8192;
        #pragma unroll 4
        for (int kt = 0; kt < 16; ++kt) {
          bf16x8 afr[4];
          #pragma unroll
          for (int i = 0; i < 4; ++i)
            afr[i] = *(const bf16x8*)swzh1(h1, i * 16 + l16, kt * 32 + quad * 8);
          #pragma unroll
          for (int ct = 0; ct < 2; ++ct) {
            bf16x8 bfr = *(const bf16x8*)(Wc + (((size_t)ct * 16 + kt) * 64 + lane) * 8);
            #pragma unroll
            for (int i = 0; i < 4; ++i) acc[i][ct] = mfma16(afr[i], bfr, acc[i][ct]);
          }
        }
        // stage in two 128-col halves (cols cg<4 then cg>=4)
        #pragma unroll
        for (int hh = 0; hh < 2; ++hh) {
          __syncthreads();
          if ((wv >> 2) == hh) {
            int cgl = wv & 3;
            #pragma unroll
            for (int i = 0; i < 4; ++i)
              #pragma unroll
              for (int ct = 0; ct < 2; ++ct)
                #pragma unroll
                for (int r = 0; r < 4; ++r)
                  *swzh2(h2c, i * 16 + quad * 4 + r, cgl * 32 + ct * 16 + l16) =
                      (__bf16)fmaxf(acc[i][ct][r], 0.f);
          }
          __syncthreads();
          if (wv < 4) {
            #pragma unroll
            for (int k2 = 0; k2 < 4; ++k2) {
              bf16x8 afr2 = *(const bf16x8*)swzh2(h2c, wv * 16 + l16,
                                                  k2 * 32 + quad * 8);
              bf16x8 bfr2 = *(const bf16x8*)(W2 + ((size_t)(cc2 * 8 + hh * 4 + k2) * 64 + lane) * 8);
              po = mfma16(afr2, bfr2, po);
            }
          }
        }
      }
      // pose epilogue: accumulate into registers across ensembles
      if (wv < 4 && l16 < 13) {
        float sc = sigma_t_pose[l16] + 1e-8f;
        float mv = mu_t_pose[l16];
        #pragma unroll
        for (int r = 0; r < 4; ++r) {
          int row = wv * 16 + quad * 4 + r;
          posacc[r] += po[r] * sc + mv + se[(size_t)(b0 + row) * 29 + l16];
        }
      }
    }
  } // e

  // ================= final writes: mean over ensembles =================
  if (wv < 4 && l16 < 13) {
    #pragma unroll
    for (int r = 0; r < 4; ++r) {
      int row = wv * 16 + quad * 4 + r;
      out[(size_t)(b0 + row) * 29 + l16] = 0.25f * posacc[r];
    }
  }
  for (int i = tid; i < 64 * 16; i += 512) {
    int t = i >> 4, k = i & 15;
    out[(size_t)(b0 + t) * 29 + 13 + k] = 0.25f * legacc[t][k];
  }
}

// ---------------- launch ----------------------------------------------------
extern "C" void kernel_launch(void* const* d_in, const int* in_sizes, int n_in,
                              void* d_out, int out_size, void* d_ws, size_t ws_size,
                              hipStream_t stream) {
  const float* state = (const float*)d_in[0];
  const float* act = (const float*)d_in[1];
  const float* wl0 = (const float*)d_in[2];
  const float* bl0 = (const float*)d_in[3];
  const float* wl1 = (const float*)d_in[4];
  const float* bl1 = (const float*)d_in[5];
  const float* wl2 = (const float*)d_in[6];
  const float* bl2 = (const float*)d_in[7];
  const float* wp0 = (const float*)d_in[8];
  const float* bp0 = (const float*)d_in[9];
  const float* wp1 = (const float*)d_in[10];
  const float* bp1 = (const float*)d_in[11];
  const float* wp2 = (const float*)d_in[12];
  const float* bp2 = (const float*)d_in[13];
  const float* mu_leg = (const float*)d_in[14];
  const float* sigma_leg = (const float*)d_in[15];
  const float* mu_pose = (const float*)d_in[16];
  const float* sigma_pose = (const float*)d_in[17];
  const float* mu_t_leg = (const float*)d_in[18];
  const float* sigma_t_leg = (const float*)d_in[19];
  const float* mu_t_pose = (const float*)d_in[20];
  const float* sigma_t_pose = (const float*)d_in[21];
  float* out = (float*)d_out;

  char* ws = (char*)d_ws;
  __bf16* WL0p = (__bf16*)(ws);
  __bf16* WL1p = (__bf16*)(ws + 131072);
  __bf16* WL2p = (__bf16*)(ws + 2228224);
  __bf16* WP0p = (__bf16*)(ws + 2293760);
  __bf16* WP1p = (__bf16*)(ws + 2424832);
  __bf16* WP2p = (__bf16*)(ws + 4521984);
  float* bl0f = (float*)(ws + 4587520);
  float* bp0f = (float*)(ws + 4595712);

  prep_small<<<256, 256, 0, stream>>>(wl0, wl2, wp0, wp2, bl0, bp0,
                                      mu_leg, sigma_leg, mu_pose, sigma_pose,
                                      WL0p, WL2p, WP0p, WP2p, bl0f, bp0f);
  prep_w1<<<256, 256, 0, stream>>>(wl1, wp1, WL1p, WP1p);
  fused_kernel<<<256, 512, 0, stream>>>(state, act, bl1, bl2, bp1, bp2,
                                        mu_t_leg, sigma_t_leg, mu_t_pose, sigma_t_pose,
                                        WL0p, WL1p, WL2p, WP0p, WP1p, WP2p,
                                        bl0f, bp0f, out);
}

// Round 5
// 537.473 us; speedup vs baseline: 1.6409x; 1.0939x over previous
//
#include <hip/hip_runtime.h>

// NPG model: E=4 ensembles, B=16384, STATE=29, ACT=8, HID=512.
// R7 = R6 resubmitted verbatim (R4 bench was an infra container failure, no
// kernel verdict). R6 = exact R2 fused structure (256 blocks x 64 rows x
// 8 waves, 1 block/CU, lockstep weight stream, 281us proven) + ONE change:
//   h1/h2c padded strides (520/136) -> linear 512/128 with element-index
//   swizzle  idx = (row<<9) | (col ^ (f(row)<<3)),
//   f(row) = ((row&7) + ((row>>2)&2)) & 7.
//   The +2 term for rows 8..15 separates quad pairs: C-frag u16 writes
//   (rows quad*4+r) land on disjoint 16B slots -> kills the 4-way write
//   conflicts that produced ALL of R2's 2.3e7 SQ_LDS_BANK_CONFLICT (count
//   was bit-identical under the (row&7)-only swizzle, which cannot separate
//   rows 8 apart). 16-row read windows hit each slot exactly 2x -> reads
//   stay free (2-way is free per m136). NO pointer casts (the char* swizzle
//   helpers of R3/R4/R5 correlated with VGPR 96->128 + 40-438MB of
//   scratch-class TCC traffic).
// Prep: R5's split prep (coalesced W1 strip packer) kept.

#define E_ 4
#define B_ 16384
#define A0S 40    // a0 row stride (unswizzled, aliases h2c)

typedef float f32x4 __attribute__((ext_vector_type(4)));
typedef __bf16 bf16x8 __attribute__((ext_vector_type(8)));

__device__ __forceinline__ f32x4 mfma16(bf16x8 a, bf16x8 b, f32x4 c) {
  return __builtin_amdgcn_mfma_f32_16x16x32_bf16(a, b, c, 0, 0, 0);
}

// element-space XOR key: f(row)<<3 elements = f(row)<<4 bytes (16B slots)
__device__ __forceinline__ int fswz(int row) {
  return (((row & 7) + ((row >> 2) & 2)) & 7) << 3;
}
// h1: 512-col rows; col^key stays <512, bits0-2 preserved (b128-safe)
__device__ __forceinline__ int h1i(int row, int col) {
  return (row << 9) | (col ^ fswz(row));
}
// h2c: 128-col rows
__device__ __forceinline__ int h2i(int row, int col) {
  return (row << 7) | (col ^ fswz(row));
}

// leg-format position mapping: output slot 13+k <- leg-block ib, component j
__device__ __forceinline__ void fmt_map(int k, int& ib, int& j) {
  if (k < 8) { ib = k >> 1; j = (k & 1) ? 2 : 0; }
  else { int k8 = k - 8; ib = k8 >> 1; j = (k8 & 1) ? 3 : 1; }
}

// ---------------- prep: pack weights into bf16 MFMA-B-fragment order --------
// Packed W (K x N): tiles (nt,kt) of 32x16; element ((nt*KT+kt)*64+lane)*8+j
// holds W[kt*32 + (lane>>4)*8 + j][nt*16 + (lane&15)]
__device__ __forceinline__ void pack_one(int idx, int per_e, int KT, int Kreal,
                                         int Nsrc, int Nval,
                                         const float* __restrict__ src,
                                         const float* __restrict__ sigma,
                                         __bf16* __restrict__ dst)
{
  int e = idx / per_e;
  int rem = idx - e * per_e;
  int g = rem >> 9;            // nt*KT + kt
  int nt = g / KT;
  int kt = g - nt * KT;
  int li = rem & 511;
  int lane = li >> 3, j = li & 7;
  int k = kt * 32 + (lane >> 4) * 8 + j;
  int n = nt * 16 + (lane & 15);
  float v = 0.f;
  if (k < Kreal && n < Nval) {
    v = src[(size_t)e * Kreal * Nsrc + (size_t)k * Nsrc + n];
    if (sigma) v *= 1.f / (sigma[k] + 1e-8f);   // fold input normalization
  }
  dst[idx] = (__bf16)v;
}

// Small matrices (W0 x2, W2 x2) + bias folds: gather path (cheap, cached).
__global__ void prep_small(const float* __restrict__ wl0, const float* __restrict__ wl2,
                           const float* __restrict__ wp0, const float* __restrict__ wp2,
                           const float* __restrict__ bl0, const float* __restrict__ bp0,
                           const float* __restrict__ mu_leg, const float* __restrict__ sigma_leg,
                           const float* __restrict__ mu_pose, const float* __restrict__ sigma_pose,
                           __bf16* __restrict__ WL0p, __bf16* __restrict__ WL2p,
                           __bf16* __restrict__ WP0p, __bf16* __restrict__ WP2p,
                           float* __restrict__ bl0f, float* __restrict__ bp0f)
{
  const int S0 = 65536, S2 = 32768;
  const int total = 2 * (S0 + S2) + 4096;
  for (int idx0 = blockIdx.x * blockDim.x + threadIdx.x; idx0 < total;
       idx0 += gridDim.x * blockDim.x) {
    int x = idx0;
    if (x < S0)              { pack_one(x, 16384, 1, 6, 512, 512, wl0, sigma_leg, WL0p); }
    else if ((x -= S0) < S2) { pack_one(x, 8192, 16, 512, 8, 8, wl2, nullptr, WL2p); }
    else if ((x -= S2) < S0) { pack_one(x, 16384, 1, 29, 512, 512, wp0, sigma_pose, WP0p); }
    else if ((x -= S0) < S2) { pack_one(x, 8192, 16, 512, 26, 16, wp2, nullptr, WP2p); }
    else {
      x -= S2;  // bias folds: b0' = b0 - sum_k mu[k]/(sigma[k]+eps) * W0[k,:]
      if (x < 2048) {
        int e = x >> 9, n = x & 511;
        float s = bl0[e * 512 + n];
        #pragma unroll
        for (int k = 0; k < 6; ++k)
          s -= mu_leg[k] / (sigma_leg[k] + 1e-8f) * wl0[(e * 6 + k) * 512 + n];
        bl0f[e * 512 + n] = s;
      } else {
        x -= 2048;
        int e = x >> 9, n = x & 511;
        float s = bp0[e * 512 + n];
        for (int k = 0; k < 29; ++k)
          s -= mu_pose[k] / (sigma_pose[k] + 1e-8f) * wp0[(e * 29 + k) * 512 + n];
        bp0f[e * 512 + n] = s;
      }
    }
  }
}

// W1 matrices (512x512): coalesced strip packer. Block = one (mat,e,nt)
// 512x16 column strip; stage f32->bf16 in LDS coalesced, emit contiguous.
__global__ __launch_bounds__(256) void prep_w1(const float* __restrict__ wl1,
                                               const float* __restrict__ wp1,
                                               __bf16* __restrict__ WL1p,
                                               __bf16* __restrict__ WP1p)
{
  __shared__ __bf16 st[512][20];
  const int b = blockIdx.x;          // 0..255: [mat(1) | e(2) | nt(5)]
  const float* src = (b & 128) ? wp1 : wl1;
  __bf16* dst = (b & 128) ? WP1p : WL1p;
  const int e = (b >> 5) & 3, nt = b & 31;
  src += (size_t)e * 262144 + nt * 16;
  dst += (size_t)e * 262144 + (size_t)nt * 8192;
  const int t = threadIdx.x;

  const int k0 = t >> 2, nq = t & 3;
  #pragma unroll
  for (int it = 0; it < 8; ++it) {
    int k = it * 64 + k0;
    f32x4 v = *(const f32x4*)(src + (size_t)k * 512 + nq * 4);
    #pragma unroll
    for (int j = 0; j < 4; ++j) st[k][nq * 4 + j] = (__bf16)v[j];
  }
  __syncthreads();
  #pragma unroll
  for (int it = 0; it < 4; ++it) {
    int lo = it * 256 + t;           // bf16x8 index 0..1023
    int kt = lo >> 6, lane = lo & 63;
    int kb = kt * 32 + (lane >> 4) * 8;
    int n = lane & 15;
    bf16x8 o;
    #pragma unroll
    for (int j = 0; j < 8; ++j) o[j] = st[kb + j][n];
    *(bf16x8*)(dst + (size_t)lo * 8) = o;
  }
}

// ---------------- fused model kernel (R2 structure + index swizzle) ---------
__global__ __launch_bounds__(512) void fused_kernel(
    const float* __restrict__ state, const float* __restrict__ act,
    const float* __restrict__ bl1, const float* __restrict__ bl2,
    const float* __restrict__ bp1, const float* __restrict__ bp2,
    const float* __restrict__ mu_t_leg, const float* __restrict__ sigma_t_leg,
    const float* __restrict__ mu_t_pose, const float* __restrict__ sigma_t_pose,
    const __bf16* __restrict__ WL0p, const __bf16* __restrict__ WL1p,
    const __bf16* __restrict__ WL2p, const __bf16* __restrict__ WP0p,
    const __bf16* __restrict__ WP1p, const __bf16* __restrict__ WP2p,
    const float* __restrict__ bl0f, const float* __restrict__ bp0f,
    float* __restrict__ out)
{
  __shared__ alignas(16) __bf16 h1[128 * 512];   // 131072 B, index-swizzled
  __shared__ alignas(16) __bf16 h2c[64 * 128];   // 16384 B (union with a0)
  __shared__ float ldiff[64][16];                // 4096 B
  __shared__ float legacc[64][16];               // 4096 B  -> total 155648 B
  __bf16* a0s = h2c;                             // a0 = 128*40 elems, fits

  const int tid = threadIdx.x;
  const int wv = tid >> 6;        // wave 0..7
  const int lane = tid & 63;
  const int quad = lane >> 4;
  const int l16 = lane & 15;
  const int b0 = blockIdx.x * 64;

  for (int i = tid; i < 64 * 16; i += 512) ((float*)legacc)[i] = 0.f;
  f32x4 posacc = {0.f, 0.f, 0.f, 0.f};
  __syncthreads();

  for (int e = 0; e < E_; ++e) {
    const float* se = state + (size_t)e * B_ * 29;
    const float* ae = act + (size_t)e * B_ * 8;

    // ================= leg MLP: 2 passes of 128 leg rows =================
    for (int half = 0; half < 2; ++half) {
      __syncthreads();   // h2c/a0 region free (prior readers done)
      // ---- a0 build: 128 rows (ib*32+t) x 32 cols (6 real)
      for (int i = tid; i < 128 * 32; i += 512) {
        int r = i >> 5, c = i & 31;
        float v = 0.f;
        if (c < 6) {
          int ib = r >> 5;
          int b = b0 + half * 32 + (r & 31);
          const float* sp = se + (size_t)b * 29;
          if (c == 0) v = sp[13 + 2 * ib];
          else if (c == 1) v = sp[21 + 2 * ib];
          else if (c == 2) v = sp[14 + 2 * ib];
          else if (c == 3) v = sp[22 + 2 * ib];
          else if (c == 4) v = ae[(size_t)b * 8 + 2 * ib];
          else v = ae[(size_t)b * 8 + 2 * ib + 1];
        }
        a0s[r * A0S + c] = (__bf16)v;
      }
      __syncthreads();

      // ---- layer0: h1(128x512) = relu(A0 @ W0 + b0'); wave owns 4 col-tiles
      {
        const __bf16* W0 = WL0p + (size_t)e * 16384;
        const float* b0v = bl0f + e * 512;
        bf16x8 bfr[4]; float bs[4];
        #pragma unroll
        for (int i = 0; i < 4; ++i) {
          int ct = wv * 4 + i;
          bfr[i] = *(const bf16x8*)(W0 + ((size_t)ct * 64 + lane) * 8);
          bs[i] = b0v[ct * 16 + l16];
        }
        for (int rt = 0; rt < 8; ++rt) {
          bf16x8 afr = *(const bf16x8*)&a0s[(rt * 16 + l16) * A0S + quad * 8];
          #pragma unroll
          for (int i = 0; i < 4; ++i) {
            f32x4 acc = {bs[i], bs[i], bs[i], bs[i]};
            acc = mfma16(afr, bfr[i], acc);
            int col = (wv * 4 + i) * 16 + l16;
            #pragma unroll
            for (int r = 0; r < 4; ++r)
              h1[h1i(rt * 16 + quad * 4 + r, col)] = (__bf16)fmaxf(acc[r], 0.f);
          }
        }
      }
      __syncthreads();

      // ---- layer1 (128x512x512) + fused layer2; wave tile 64r x 32c
      const __bf16* W1 = WL1p + (size_t)e * 262144;
      const __bf16* W2 = WL2p + (size_t)e * 8192;
      const float* b1v = bl1 + e * 512;
      const int rg = wv >> 2, cg = wv & 3;
      float bv2 = (l16 < 8) ? bl2[e * 8 + l16] : 0.f;
      f32x4 oacc = {bv2, bv2, bv2, bv2};     // wave wv owns row-tile wv (l2)

      for (int cc = 0; cc < 4; ++cc) {
        f32x4 acc[4][2];
        #pragma unroll
        for (int ct = 0; ct < 2; ++ct) {
          float bias = b1v[cc * 128 + cg * 32 + ct * 16 + l16];
          #pragma unroll
          for (int i = 0; i < 4; ++i) acc[i][ct] = (f32x4){bias, bias, bias, bias};
        }
        const __bf16* Wc = W1 + (size_t)(cc * 8 + cg * 2) * 8192;
        #pragma unroll 4
        for (int kt = 0; kt < 16; ++kt) {
          bf16x8 afr[4];
          #pragma unroll
          for (int i = 0; i < 4; ++i)
            afr[i] = *(const bf16x8*)&h1[h1i(rg * 64 + i * 16 + l16,
                                             kt * 32 + quad * 8)];
          #pragma unroll
          for (int ct = 0; ct < 2; ++ct) {
            bf16x8 bfr = *(const bf16x8*)(Wc + (((size_t)ct * 16 + kt) * 64 + lane) * 8);
            #pragma unroll
            for (int i = 0; i < 4; ++i) acc[i][ct] = mfma16(afr[i], bfr, acc[i][ct]);
          }
        }
        // stage h2 in two 64-row halves; owners accumulate layer2
        #pragma unroll
        for (int hh = 0; hh < 2; ++hh) {
          __syncthreads();
          if (rg == hh) {
            #pragma unroll
            for (int i = 0; i < 4; ++i)
              #pragma unroll
              for (int ct = 0; ct < 2; ++ct)
                #pragma unroll
                for (int r = 0; r < 4; ++r)
                  h2c[h2i(i * 16 + quad * 4 + r, cg * 32 + ct * 16 + l16)] =
                      (__bf16)fmaxf(acc[i][ct][r], 0.f);
          }
          __syncthreads();
          if ((wv >> 2) == hh) {
            #pragma unroll
            for (int k2 = 0; k2 < 4; ++k2) {
              bf16x8 afr2 = *(const bf16x8*)&h2c[h2i((wv & 3) * 16 + l16,
                                                     k2 * 32 + quad * 8)];
              bf16x8 bfr2 = *(const bf16x8*)(W2 + ((size_t)(cc * 4 + k2) * 64 + lane) * 8);
              oacc = mfma16(afr2, bfr2, oacc);
            }
          }
        }
      }
      // ---- leg epilogue: ldiff (only first 4 outputs used)
      if (l16 < 4) {
        float sc = sigma_t_leg[l16] + 1e-8f;
        float mv = mu_t_leg[l16];
        #pragma unroll
        for (int r = 0; r < 4; ++r) {
          int L = wv * 16 + quad * 4 + r;    // leg row = ib*32 + t
          ldiff[half * 32 + (L & 31)][(L >> 5) * 4 + l16] = oacc[r] * sc + mv;
        }
      }
    } // half

    // ================= pose MLP: 64 rows =================
    __syncthreads();   // ldiff ready, h2c free
    for (int i = tid; i < 64 * 32; i += 512) {
      int t = i >> 5, c = i & 31;
      float v = 0.f;
      if (c < 13) v = se[(size_t)(b0 + t) * 29 + c];
      else if (c < 29) { int ib, j; fmt_map(c - 13, ib, j); v = ldiff[t][ib * 4 + j]; }
      a0s[t * A0S + c] = (__bf16)v;
    }
    for (int i = tid; i < 64 * 16; i += 512) {   // legs output accumulation
      int t = i >> 4, k = i & 15;
      int ib, j; fmt_map(k, ib, j);
      legacc[t][k] += se[(size_t)(b0 + t) * 29 + 13 + k] + ldiff[t][ib * 4 + j];
    }
    __syncthreads();

    // ---- pose layer0: h1(64x512)
    {
      const __bf16* W0 = WP0p + (size_t)e * 16384;
      const float* b0v = bp0f + e * 512;
      bf16x8 bfr[4]; float bs[4];
      #pragma unroll
      for (int i = 0; i < 4; ++i) {
        int ct = wv * 4 + i;
        bfr[i] = *(const bf16x8*)(W0 + ((size_t)ct * 64 + lane) * 8);
        bs[i] = b0v[ct * 16 + l16];
      }
      for (int rt = 0; rt < 4; ++rt) {
        bf16x8 afr = *(const bf16x8*)&a0s[(rt * 16 + l16) * A0S + quad * 8];
        #pragma unroll
        for (int i = 0; i < 4; ++i) {
          f32x4 acc = {bs[i], bs[i], bs[i], bs[i]};
          acc = mfma16(afr, bfr[i], acc);
          int col = (wv * 4 + i) * 16 + l16;
          #pragma unroll
          for (int r = 0; r < 4; ++r)
            h1[h1i(rt * 16 + quad * 4 + r, col)] = (__bf16)fmaxf(acc[r], 0.f);
        }
      }
    }
    __syncthreads();

    // ---- pose layer1 (64x512x512) + fused layer2 (N=13 -> 1 col-tile)
    {
      const __bf16* W1 = WP1p + (size_t)e * 262144;
      const __bf16* W2 = WP2p + (size_t)e * 8192;
      const float* b1v = bp1 + e * 512;
      float bvp = bp2[e * 26 + l16];
      f32x4 po = {bvp, bvp, bvp, bvp};       // waves 0..3 own row-tiles 0..3

      for (int cc2 = 0; cc2 < 2; ++cc2) {
        f32x4 acc[4][2];
        #pragma unroll
        for (int ct = 0; ct < 2; ++ct) {
          float bias = b1v[cc2 * 256 + wv * 32 + ct * 16 + l16];
          #pragma unroll
          for (int i = 0; i < 4; ++i) acc[i][ct] = (f32x4){bias, bias, bias, bias};
        }
        const __bf16* Wc = W1 + (size_t)(cc2 * 16 + wv * 2) * 8192;
        #pragma unroll 4
        for (int kt = 0; kt < 16; ++kt) {
          bf16x8 afr[4];
          #pragma unroll
          for (int i = 0; i < 4; ++i)
            afr[i] = *(const bf16x8*)&h1[h1i(i * 16 + l16, kt * 32 + quad * 8)];
          #pragma unroll
          for (int ct = 0; ct < 2; ++ct) {
            bf16x8 bfr = *(const bf16x8*)(Wc + (((size_t)ct * 16 + kt) * 64 + lane) * 8);
            #pragma unroll
            for (int i = 0; i < 4; ++i) acc[i][ct] = mfma16(afr[i], bfr, acc[i][ct]);
          }
        }
        // stage in two 128-col halves (cols cg<4 then cg>=4)
        #pragma unroll
        for (int hh = 0; hh < 2; ++hh) {
          __syncthreads();
          if ((wv >> 2) == hh) {
            int cgl = wv & 3;
            #pragma unroll
            for (int i = 0; i < 4; ++i)
              #pragma unroll
              for (int ct = 0; ct < 2; ++ct)
                #pragma unroll
                for (int r = 0; r < 4; ++r)
                  h2c[h2i(i * 16 + quad * 4 + r, cgl * 32 + ct * 16 + l16)] =
                      (__bf16)fmaxf(acc[i][ct][r], 0.f);
          }
          __syncthreads();
          if (wv < 4) {
            #pragma unroll
            for (int k2 = 0; k2 < 4; ++k2) {
              bf16x8 afr2 = *(const bf16x8*)&h2c[h2i(wv * 16 + l16,
                                                     k2 * 32 + quad * 8)];
              bf16x8 bfr2 = *(const bf16x8*)(W2 + ((size_t)(cc2 * 8 + hh * 4 + k2) * 64 + lane) * 8);
              po = mfma16(afr2, bfr2, po);
            }
          }
        }
      }
      // pose epilogue: accumulate into registers across ensembles
      if (wv < 4 && l16 < 13) {
        float sc = sigma_t_pose[l16] + 1e-8f;
        float mv = mu_t_pose[l16];
        #pragma unroll
        for (int r = 0; r < 4; ++r) {
          int row = wv * 16 + quad * 4 + r;
          posacc[r] += po[r] * sc + mv + se[(size_t)(b0 + row) * 29 + l16];
        }
      }
    }
  } // e

  // ================= final writes: mean over ensembles =================
  if (wv < 4 && l16 < 13) {
    #pragma unroll
    for (int r = 0; r < 4; ++r) {
      int row = wv * 16 + quad * 4 + r;
      out[(size_t)(b0 + row) * 29 + l16] = 0.25f * posacc[r];
    }
  }
  for (int i = tid; i < 64 * 16; i += 512) {
    int t = i >> 4, k = i & 15;
    out[(size_t)(b0 + t) * 29 + 13 + k] = 0.25f * legacc[t][k];
  }
}

// ---------------- launch ----------------------------------------------------
extern "C" void kernel_launch(void* const* d_in, const int* in_sizes, int n_in,
                              void* d_out, int out_size, void* d_ws, size_t ws_size,
                              hipStream_t stream) {
  const float* state = (const float*)d_in[0];
  const float* act = (const float*)d_in[1];
  const float* wl0 = (const float*)d_in[2];
  const float* bl0 = (const float*)d_in[3];
  const float* wl1 = (const float*)d_in[4];
  const float* bl1 = (const float*)d_in[5];
  const float* wl2 = (const float*)d_in[6];
  const float* bl2 = (const float*)d_in[7];
  const float* wp0 = (const float*)d_in[8];
  const float* bp0 = (const float*)d_in[9];
  const float* wp1 = (const float*)d_in[10];
  const float* bp1 = (const float*)d_in[11];
  const float* wp2 = (const float*)d_in[12];
  const float* bp2 = (const float*)d_in[13];
  const float* mu_leg = (const float*)d_in[14];
  const float* sigma_leg = (const float*)d_in[15];
  const float* mu_pose = (const float*)d_in[16];
  const float* sigma_pose = (const float*)d_in[17];
  const float* mu_t_leg = (const float*)d_in[18];
  const float* sigma_t_leg = (const float*)d_in[19];
  const float* mu_t_pose = (const float*)d_in[20];
  const float* sigma_t_pose = (const float*)d_in[21];
  float* out = (float*)d_out;

  char* ws = (char*)d_ws;
  __bf16* WL0p = (__bf16*)(ws);
  __bf16* WL1p = (__bf16*)(ws + 131072);
  __bf16* WL2p = (__bf16*)(ws + 2228224);
  __bf16* WP0p = (__bf16*)(ws + 2293760);
  __bf16* WP1p = (__bf16*)(ws + 2424832);
  __bf16* WP2p = (__bf16*)(ws + 4521984);
  float* bl0f = (float*)(ws + 4587520);
  float* bp0f = (float*)(ws + 4595712);

  prep_small<<<256, 256, 0, stream>>>(wl0, wl2, wp0, wp2, bl0, bp0,
                                      mu_leg, sigma_leg, mu_pose, sigma_pose,
                                      WL0p, WL2p, WP0p, WP2p, bl0f, bp0f);
  prep_w1<<<256, 256, 0, stream>>>(wl1, wp1, WL1p, WP1p);
  fused_kernel<<<256, 512, 0, stream>>>(state, act, bl1, bl2, bp1, bp2,
                                        mu_t_leg, sigma_t_leg, mu_t_pose, sigma_t_pose,
                                        WL0p, WL1p, WL2p, WP0p, WP1p, WP2p,
                                        bl0f, bp0f, out);
}

// Round 6
// 373.078 us; speedup vs baseline: 2.3640x; 1.4406x over previous
//
#include <hip/hip_runtime.h>

// NPG model: E=4 ensembles, B=16384, STATE=29, ACT=8, HID=512.
// R8 = R2 structure VERBATIM (256 blocks x 64 rows x 8 waves, 1 block/CU,
// padded LDS strides 520/136, 96-VGPR-class codegen, 281us proven) with ONE
// structural change: L1 wave tile widened 64rx32c -> 64rx64c (leg cc 4->2,
// ct 2->4; pose one 64-col strip/wave). Same 4 afr b128 reads per kt now
// feed 16 MFMAs (was 8) -> L1 A-frag LDS reads HALVE. Rationale: bank-
// conflict counter was bit-identical (2.307e7) across three different
// h1/h2c layouts (R2/R5/R7) -> conflicts are intrinsic wave64-b128
// multi-cycle behavior, unfixable by swizzle, only reducible by issuing
// fewer b128 reads. Staging keeps 128-col granularity (h2c/barriers
// unchanged); W2 k-tile indices remapped (leg: cc*8+k2*2+sc, pose: sr*4+k2).
// kt unroll 4->2 to hold register pressure (acc[4][2]->acc[4][4], +32 VGPR).
// Prep: R5/R7 split prep kept (passed twice).

#define E_ 4
#define B_ 16384
#define H1S 520   // h1 row stride (bf16 elems), 16B-aligned
#define H2S 136   // h2 staging row stride
#define A0S 40    // a0 row stride

typedef float f32x4 __attribute__((ext_vector_type(4)));
typedef __bf16 bf16x8 __attribute__((ext_vector_type(8)));

__device__ __forceinline__ f32x4 mfma16(bf16x8 a, bf16x8 b, f32x4 c) {
  return __builtin_amdgcn_mfma_f32_16x16x32_bf16(a, b, c, 0, 0, 0);
}

// leg-format position mapping: output slot 13+k <- leg-block ib, component j
__device__ __forceinline__ void fmt_map(int k, int& ib, int& j) {
  if (k < 8) { ib = k >> 1; j = (k & 1) ? 2 : 0; }
  else { int k8 = k - 8; ib = k8 >> 1; j = (k8 & 1) ? 3 : 1; }
}

// ---------------- prep: pack weights into bf16 MFMA-B-fragment order --------
// Packed W (K x N): tiles (nt,kt) of 32x16; element ((nt*KT+kt)*64+lane)*8+j
// holds W[kt*32 + (lane>>4)*8 + j][nt*16 + (lane&15)]
__device__ __forceinline__ void pack_one(int idx, int per_e, int KT, int Kreal,
                                         int Nsrc, int Nval,
                                         const float* __restrict__ src,
                                         const float* __restrict__ sigma,
                                         __bf16* __restrict__ dst)
{
  int e = idx / per_e;
  int rem = idx - e * per_e;
  int g = rem >> 9;            // nt*KT + kt
  int nt = g / KT;
  int kt = g - nt * KT;
  int li = rem & 511;
  int lane = li >> 3, j = li & 7;
  int k = kt * 32 + (lane >> 4) * 8 + j;
  int n = nt * 16 + (lane & 15);
  float v = 0.f;
  if (k < Kreal && n < Nval) {
    v = src[(size_t)e * Kreal * Nsrc + (size_t)k * Nsrc + n];
    if (sigma) v *= 1.f / (sigma[k] + 1e-8f);   // fold input normalization
  }
  dst[idx] = (__bf16)v;
}

// Small matrices (W0 x2, W2 x2) + bias folds: gather path (cheap, cached).
__global__ void prep_small(const float* __restrict__ wl0, const float* __restrict__ wl2,
                           const float* __restrict__ wp0, const float* __restrict__ wp2,
                           const float* __restrict__ bl0, const float* __restrict__ bp0,
                           const float* __restrict__ mu_leg, const float* __restrict__ sigma_leg,
                           const float* __restrict__ mu_pose, const float* __restrict__ sigma_pose,
                           __bf16* __restrict__ WL0p, __bf16* __restrict__ WL2p,
                           __bf16* __restrict__ WP0p, __bf16* __restrict__ WP2p,
                           float* __restrict__ bl0f, float* __restrict__ bp0f)
{
  const int S0 = 65536, S2 = 32768;
  const int total = 2 * (S0 + S2) + 4096;
  for (int idx0 = blockIdx.x * blockDim.x + threadIdx.x; idx0 < total;
       idx0 += gridDim.x * blockDim.x) {
    int x = idx0;
    if (x < S0)              { pack_one(x, 16384, 1, 6, 512, 512, wl0, sigma_leg, WL0p); }
    else if ((x -= S0) < S2) { pack_one(x, 8192, 16, 512, 8, 8, wl2, nullptr, WL2p); }
    else if ((x -= S2) < S0) { pack_one(x, 16384, 1, 29, 512, 512, wp0, sigma_pose, WP0p); }
    else if ((x -= S0) < S2) { pack_one(x, 8192, 16, 512, 26, 16, wp2, nullptr, WP2p); }
    else {
      x -= S2;  // bias folds: b0' = b0 - sum_k mu[k]/(sigma[k]+eps) * W0[k,:]
      if (x < 2048) {
        int e = x >> 9, n = x & 511;
        float s = bl0[e * 512 + n];
        #pragma unroll
        for (int k = 0; k < 6; ++k)
          s -= mu_leg[k] / (sigma_leg[k] + 1e-8f) * wl0[(e * 6 + k) * 512 + n];
        bl0f[e * 512 + n] = s;
      } else {
        x -= 2048;
        int e = x >> 9, n = x & 511;
        float s = bp0[e * 512 + n];
        for (int k = 0; k < 29; ++k)
          s -= mu_pose[k] / (sigma_pose[k] + 1e-8f) * wp0[(e * 29 + k) * 512 + n];
        bp0f[e * 512 + n] = s;
      }
    }
  }
}

// W1 matrices (512x512): coalesced strip packer. Block = one (mat,e,nt)
// 512x16 column strip; stage f32->bf16 in LDS coalesced, emit contiguous.
__global__ __launch_bounds__(256) void prep_w1(const float* __restrict__ wl1,
                                               const float* __restrict__ wp1,
                                               __bf16* __restrict__ WL1p,
                                               __bf16* __restrict__ WP1p)
{
  __shared__ __bf16 st[512][20];
  const int b = blockIdx.x;          // 0..255: [mat(1) | e(2) | nt(5)]
  const float* src = (b & 128) ? wp1 : wl1;
  __bf16* dst = (b & 128) ? WP1p : WL1p;
  const int e = (b >> 5) & 3, nt = b & 31;
  src += (size_t)e * 262144 + nt * 16;
  dst += (size_t)e * 262144 + (size_t)nt * 8192;
  const int t = threadIdx.x;

  const int k0 = t >> 2, nq = t & 3;
  #pragma unroll
  for (int it = 0; it < 8; ++it) {
    int k = it * 64 + k0;
    f32x4 v = *(const f32x4*)(src + (size_t)k * 512 + nq * 4);
    #pragma unroll
    for (int j = 0; j < 4; ++j) st[k][nq * 4 + j] = (__bf16)v[j];
  }
  __syncthreads();
  #pragma unroll
  for (int it = 0; it < 4; ++it) {
    int lo = it * 256 + t;           // bf16x8 index 0..1023
    int kt = lo >> 6, lane = lo & 63;
    int kb = kt * 32 + (lane >> 4) * 8;
    int n = lane & 15;
    bf16x8 o;
    #pragma unroll
    for (int j = 0; j < 8; ++j) o[j] = st[kb + j][n];
    *(bf16x8*)(dst + (size_t)lo * 8) = o;
  }
}

// ---------------- fused model kernel ----------------------------------------
__global__ __launch_bounds__(512) void fused_kernel(
    const float* __restrict__ state, const float* __restrict__ act,
    const float* __restrict__ bl1, const float* __restrict__ bl2,
    const float* __restrict__ bp1, const float* __restrict__ bp2,
    const float* __restrict__ mu_t_leg, const float* __restrict__ sigma_t_leg,
    const float* __restrict__ mu_t_pose, const float* __restrict__ sigma_t_pose,
    const __bf16* __restrict__ WL0p, const __bf16* __restrict__ WL1p,
    const __bf16* __restrict__ WL2p, const __bf16* __restrict__ WP0p,
    const __bf16* __restrict__ WP1p, const __bf16* __restrict__ WP2p,
    const float* __restrict__ bl0f, const float* __restrict__ bp0f,
    float* __restrict__ out)
{
  __shared__ alignas(16) __bf16 h1[128 * H1S];   // 133120 B
  __shared__ alignas(16) __bf16 h2c[64 * H2S];   // 17408 B (union with a0)
  __shared__ float ldiff[64][16];                // 4096 B
  __shared__ float legacc[64][16];               // 4096 B  -> total 158 KB
  __bf16* a0s = h2c;                             // a0 <=128*40=5120 elems, fits

  const int tid = threadIdx.x;
  const int wv = tid >> 6;        // wave 0..7
  const int lane = tid & 63;
  const int quad = lane >> 4;
  const int l16 = lane & 15;
  const int b0 = blockIdx.x * 64;

  for (int i = tid; i < 64 * 16; i += 512) ((float*)legacc)[i] = 0.f;
  f32x4 posacc = {0.f, 0.f, 0.f, 0.f};
  __syncthreads();

  for (int e = 0; e < E_; ++e) {
    const float* se = state + (size_t)e * B_ * 29;
    const float* ae = act + (size_t)e * B_ * 8;

    // ================= leg MLP: 2 passes of 128 leg rows =================
    for (int half = 0; half < 2; ++half) {
      __syncthreads();   // h2c/a0 region free (prior readers done)
      // ---- a0 build: 128 rows (ib*32+t) x 32 cols (6 real)
      for (int i = tid; i < 128 * 32; i += 512) {
        int r = i >> 5, c = i & 31;
        float v = 0.f;
        if (c < 6) {
          int ib = r >> 5;
          int b = b0 + half * 32 + (r & 31);
          const float* sp = se + (size_t)b * 29;
          if (c == 0) v = sp[13 + 2 * ib];
          else if (c == 1) v = sp[21 + 2 * ib];
          else if (c == 2) v = sp[14 + 2 * ib];
          else if (c == 3) v = sp[22 + 2 * ib];
          else if (c == 4) v = ae[(size_t)b * 8 + 2 * ib];
          else v = ae[(size_t)b * 8 + 2 * ib + 1];
        }
        a0s[r * A0S + c] = (__bf16)v;
      }
      __syncthreads();

      // ---- layer0: h1(128x512) = relu(A0 @ W0 + b0'); wave owns 4 col-tiles
      {
        const __bf16* W0 = WL0p + (size_t)e * 16384;
        const float* b0v = bl0f + e * 512;
        bf16x8 bfr[4]; float bs[4];
        #pragma unroll
        for (int i = 0; i < 4; ++i) {
          int ct = wv * 4 + i;
          bfr[i] = *(const bf16x8*)(W0 + ((size_t)ct * 64 + lane) * 8);
          bs[i] = b0v[ct * 16 + l16];
        }
        for (int rt = 0; rt < 8; ++rt) {
          bf16x8 afr = *(const bf16x8*)&a0s[(rt * 16 + l16) * A0S + quad * 8];
          #pragma unroll
          for (int i = 0; i < 4; ++i) {
            f32x4 acc = {bs[i], bs[i], bs[i], bs[i]};
            acc = mfma16(afr, bfr[i], acc);
            int col = (wv * 4 + i) * 16 + l16;
            #pragma unroll
            for (int r = 0; r < 4; ++r)
              h1[(rt * 16 + quad * 4 + r) * H1S + col] = (__bf16)fmaxf(acc[r], 0.f);
          }
        }
      }
      __syncthreads();

      // ---- layer1 (128x512x512) + fused layer2; wave tile 64r x 64c
      const __bf16* W1 = WL1p + (size_t)e * 262144;
      const __bf16* W2 = WL2p + (size_t)e * 8192;
      const float* b1v = bl1 + e * 512;
      const int rg = wv >> 2, cg = wv & 3;
      float bv2 = (l16 < 8) ? bl2[e * 8 + l16] : 0.f;
      f32x4 oacc = {bv2, bv2, bv2, bv2};     // wave wv owns row-tile wv (l2)

      for (int cc = 0; cc < 2; ++cc) {
        f32x4 acc[4][4];
        #pragma unroll
        for (int ct = 0; ct < 4; ++ct) {
          float bias = b1v[cc * 256 + cg * 64 + ct * 16 + l16];
          #pragma unroll
          for (int i = 0; i < 4; ++i) acc[i][ct] = (f32x4){bias, bias, bias, bias};
        }
        const __bf16* Wc = W1 + (size_t)(cc * 16 + cg * 4) * 8192;
        #pragma unroll 2
        for (int kt = 0; kt < 16; ++kt) {
          bf16x8 afr[4];
          #pragma unroll
          for (int i = 0; i < 4; ++i)
            afr[i] = *(const bf16x8*)&h1[(rg * 64 + i * 16 + l16) * H1S + kt * 32 + quad * 8];
          #pragma unroll
          for (int ct = 0; ct < 4; ++ct) {
            bf16x8 bfr = *(const bf16x8*)(Wc + (((size_t)ct * 16 + kt) * 64 + lane) * 8);
            #pragma unroll
            for (int i = 0; i < 4; ++i) acc[i][ct] = mfma16(afr[i], bfr, acc[i][ct]);
          }
        }
        // stage h2: 2 sub-chunks (sc = ct-pairs) x two 64-row halves
        #pragma unroll
        for (int sc = 0; sc < 2; ++sc) {
          #pragma unroll
          for (int hh = 0; hh < 2; ++hh) {
            __syncthreads();
            if (rg == hh) {
              #pragma unroll
              for (int i = 0; i < 4; ++i)
                #pragma unroll
                for (int c2 = 0; c2 < 2; ++c2)
                  #pragma unroll
                  for (int r = 0; r < 4; ++r)
                    h2c[(i * 16 + quad * 4 + r) * H2S + cg * 32 + c2 * 16 + l16] =
                        (__bf16)fmaxf(acc[i][sc * 2 + c2][r], 0.f);
            }
            __syncthreads();
            if ((wv >> 2) == hh) {
              // staged col k2*32+x  <->  k = cc*256 + k2*64 + sc*32 + x
              #pragma unroll
              for (int k2 = 0; k2 < 4; ++k2) {
                bf16x8 afr2 = *(const bf16x8*)&h2c[((wv & 3) * 16 + l16) * H2S + k2 * 32 + quad * 8];
                bf16x8 bfr2 = *(const bf16x8*)(W2 + ((size_t)((cc * 8 + k2 * 2 + sc) * 64 + lane)) * 8);
                oacc = mfma16(afr2, bfr2, oacc);
              }
            }
          }
        }
      }
      // ---- leg epilogue: ldiff (only first 4 outputs used)
      if (l16 < 4) {
        float sc = sigma_t_leg[l16] + 1e-8f;
        float mv = mu_t_leg[l16];
        #pragma unroll
        for (int r = 0; r < 4; ++r) {
          int L = wv * 16 + quad * 4 + r;    // leg row = ib*32 + t
          ldiff[half * 32 + (L & 31)][(L >> 5) * 4 + l16] = oacc[r] * sc + mv;
        }
      }
    } // half

    // ================= pose MLP: 64 rows =================
    __syncthreads();   // ldiff ready, h2c free
    for (int i = tid; i < 64 * 32; i += 512) {
      int t = i >> 5, c = i & 31;
      float v = 0.f;
      if (c < 13) v = se[(size_t)(b0 + t) * 29 + c];
      else if (c < 29) { int ib, j; fmt_map(c - 13, ib, j); v = ldiff[t][ib * 4 + j]; }
      a0s[t * A0S + c] = (__bf16)v;
    }
    for (int i = tid; i < 64 * 16; i += 512) {   // legs output accumulation
      int t = i >> 4, k = i & 15;
      int ib, j; fmt_map(k, ib, j);
      legacc[t][k] += se[(size_t)(b0 + t) * 29 + 13 + k] + ldiff[t][ib * 4 + j];
    }
    __syncthreads();

    // ---- pose layer0: h1(64x512)
    {
      const __bf16* W0 = WP0p + (size_t)e * 16384;
      const float* b0v = bp0f + e * 512;
      bf16x8 bfr[4]; float bs[4];
      #pragma unroll
      for (int i = 0; i < 4; ++i) {
        int ct = wv * 4 + i;
        bfr[i] = *(const bf16x8*)(W0 + ((size_t)ct * 64 + lane) * 8);
        bs[i] = b0v[ct * 16 + l16];
      }
      for (int rt = 0; rt < 4; ++rt) {
        bf16x8 afr = *(const bf16x8*)&a0s[(rt * 16 + l16) * A0S + quad * 8];
        #pragma unroll
        for (int i = 0; i < 4; ++i) {
          f32x4 acc = {bs[i], bs[i], bs[i], bs[i]};
          acc = mfma16(afr, bfr[i], acc);
          int col = (wv * 4 + i) * 16 + l16;
          #pragma unroll
          for (int r = 0; r < 4; ++r)
            h1[(rt * 16 + quad * 4 + r) * H1S + col] = (__bf16)fmaxf(acc[r], 0.f);
        }
      }
    }
    __syncthreads();

    // ---- pose layer1 (64x512x512): wave owns 64-col strip; fused layer2
    {
      const __bf16* W1 = WP1p + (size_t)e * 262144;
      const __bf16* W2 = WP2p + (size_t)e * 8192;
      const float* b1v = bp1 + e * 512;
      float bvp = bp2[e * 26 + l16];
      f32x4 po = {bvp, bvp, bvp, bvp};       // waves 0..3 own row-tiles 0..3

      f32x4 acc[4][4];
      #pragma unroll
      for (int ct = 0; ct < 4; ++ct) {
        float bias = b1v[wv * 64 + ct * 16 + l16];
        #pragma unroll
        for (int i = 0; i < 4; ++i) acc[i][ct] = (f32x4){bias, bias, bias, bias};
      }
      const __bf16* Wc = W1 + (size_t)(wv * 4) * 8192;
      #pragma unroll 2
      for (int kt = 0; kt < 16; ++kt) {
        bf16x8 afr[4];
        #pragma unroll
        for (int i = 0; i < 4; ++i)
          afr[i] = *(const bf16x8*)&h1[(i * 16 + l16) * H1S + kt * 32 + quad * 8];
        #pragma unroll
        for (int ct = 0; ct < 4; ++ct) {
          bf16x8 bfr = *(const bf16x8*)(Wc + (((size_t)ct * 16 + kt) * 64 + lane) * 8);
          #pragma unroll
          for (int i = 0; i < 4; ++i) acc[i][ct] = mfma16(afr[i], bfr, acc[i][ct]);
        }
      }
      // stage Y2 in 4 rounds of 128 cols; waves {2sr,2sr+1} write, 0..3 MFMA
      #pragma unroll
      for (int sr = 0; sr < 4; ++sr) {
        __syncthreads();
        if ((wv >> 1) == sr) {
          #pragma unroll
          for (int i = 0; i < 4; ++i)
            #pragma unroll
            for (int ct = 0; ct < 4; ++ct)
              #pragma unroll
              for (int r = 0; r < 4; ++r)
                h2c[(i * 16 + quad * 4 + r) * H2S + (wv & 1) * 64 + ct * 16 + l16] =
                    (__bf16)fmaxf(acc[i][ct][r], 0.f);
        }
        __syncthreads();
        if (wv < 4) {
          // staged col k2*32+x  <->  k = sr*128 + k2*32 + x
          #pragma unroll
          for (int k2 = 0; k2 < 4; ++k2) {
            bf16x8 afr2 = *(const bf16x8*)&h2c[(wv * 16 + l16) * H2S + k2 * 32 + quad * 8];
            bf16x8 bfr2 = *(const bf16x8*)(W2 + ((size_t)((sr * 4 + k2) * 64 + lane)) * 8);
            po = mfma16(afr2, bfr2, po);
          }
        }
      }
      // pose epilogue: accumulate into registers across ensembles
      if (wv < 4 && l16 < 13) {
        float sc = sigma_t_pose[l16] + 1e-8f;
        float mv = mu_t_pose[l16];
        #pragma unroll
        for (int r = 0; r < 4; ++r) {
          int row = wv * 16 + quad * 4 + r;
          posacc[r] += po[r] * sc + mv + se[(size_t)(b0 + row) * 29 + l16];
        }
      }
    }
  } // e

  // ================= final writes: mean over ensembles =================
  if (wv < 4 && l16 < 13) {
    #pragma unroll
    for (int r = 0; r < 4; ++r) {
      int row = wv * 16 + quad * 4 + r;
      out[(size_t)(b0 + row) * 29 + l16] = 0.25f * posacc[r];
    }
  }
  for (int i = tid; i < 64 * 16; i += 512) {
    int t = i >> 4, k = i & 15;
    out[(size_t)(b0 + t) * 29 + 13 + k] = 0.25f * legacc[t][k];
  }
}

// ---------------- launch ----------------------------------------------------
extern "C" void kernel_launch(void* const* d_in, const int* in_sizes, int n_in,
                              void* d_out, int out_size, void* d_ws, size_t ws_size,
                              hipStream_t stream) {
  const float* state = (const float*)d_in[0];
  const float* act = (const float*)d_in[1];
  const float* wl0 = (const float*)d_in[2];
  const float* bl0 = (const float*)d_in[3];
  const float* wl1 = (const float*)d_in[4];
  const float* bl1 = (const float*)d_in[5];
  const float* wl2 = (const float*)d_in[6];
  const float* bl2 = (const float*)d_in[7];
  const float* wp0 = (const float*)d_in[8];
  const float* bp0 = (const float*)d_in[9];
  const float* wp1 = (const float*)d_in[10];
  const float* bp1 = (const float*)d_in[11];
  const float* wp2 = (const float*)d_in[12];
  const float* bp2 = (const float*)d_in[13];
  const float* mu_leg = (const float*)d_in[14];
  const float* sigma_leg = (const float*)d_in[15];
  const float* mu_pose = (const float*)d_in[16];
  const float* sigma_pose = (const float*)d_in[17];
  const float* mu_t_leg = (const float*)d_in[18];
  const float* sigma_t_leg = (const float*)d_in[19];
  const float* mu_t_pose = (const float*)d_in[20];
  const float* sigma_t_pose = (const float*)d_in[21];
  float* out = (float*)d_out;

  char* ws = (char*)d_ws;
  __bf16* WL0p = (__bf16*)(ws);
  __bf16* WL1p = (__bf16*)(ws + 131072);
  __bf16* WL2p = (__bf16*)(ws + 2228224);
  __bf16* WP0p = (__bf16*)(ws + 2293760);
  __bf16* WP1p = (__bf16*)(ws + 2424832);
  __bf16* WP2p = (__bf16*)(ws + 4521984);
  float* bl0f = (float*)(ws + 4587520);
  float* bp0f = (float*)(ws + 4595712);

  prep_small<<<256, 256, 0, stream>>>(wl0, wl2, wp0, wp2, bl0, bp0,
                                      mu_leg, sigma_leg, mu_pose, sigma_pose,
                                      WL0p, WL2p, WP0p, WP2p, bl0f, bp0f);
  prep_w1<<<256, 256, 0, stream>>>(wl1, wp1, WL1p, WP1p);
  fused_kernel<<<256, 512, 0, stream>>>(state, act, bl1, bl2, bp1, bp2,
                                        mu_t_leg, sigma_t_leg, mu_t_pose, sigma_t_pose,
                                        WL0p, WL1p, WL2p, WP0p, WP1p, WP2p,
                                        bl0f, bp0f, out);
}

// Round 7
// 367.980 us; speedup vs baseline: 2.3967x; 1.0139x over previous
//
#include <hip/hip_runtime.h>

// NPG model: E=4 ensembles, B=16384, STATE=29, ACT=8, HID=512.
// R9 = recombination of the two independently-proven components:
//  - fused_kernel: R0/R2 VERBATIM (256 blocks x 64 rows x 8 waves, 1 blk/CU,
//    padded LDS 520/136, narrow 64x32 L1 wave tile, kt unroll 4, 96 VGPR,
//    281us measured twice). R8 showed the wide tile + unroll 2 = 301us
//    (bank conflicts halved but off critical path; unroll cost ~7%).
//  - prep: R5/R7/R8 split prep (prep_small gather + prep_w1 coalesced strip
//    packer), proven 3x, saves ~23us vs monolithic prep.
// Expected: fused 281, total ~353.

#define E_ 4
#define B_ 16384
#define H1S 520   // h1 row stride (bf16 elems), 16B-aligned, 2-way-bank-free
#define H2S 136   // h2 staging row stride
#define A0S 40    // a0 row stride

typedef float f32x4 __attribute__((ext_vector_type(4)));
typedef __bf16 bf16x8 __attribute__((ext_vector_type(8)));

__device__ __forceinline__ f32x4 mfma16(bf16x8 a, bf16x8 b, f32x4 c) {
  return __builtin_amdgcn_mfma_f32_16x16x32_bf16(a, b, c, 0, 0, 0);
}

// leg-format position mapping: output slot 13+k <- leg-block ib, component j
__device__ __forceinline__ void fmt_map(int k, int& ib, int& j) {
  if (k < 8) { ib = k >> 1; j = (k & 1) ? 2 : 0; }
  else { int k8 = k - 8; ib = k8 >> 1; j = (k8 & 1) ? 3 : 1; }
}

// ---------------- prep: pack weights into bf16 MFMA-B-fragment order --------
// Packed W (K x N): tiles (nt,kt) of 32x16; element ((nt*KT+kt)*64+lane)*8+j
// holds W[kt*32 + (lane>>4)*8 + j][nt*16 + (lane&15)]
__device__ __forceinline__ void pack_one(int idx, int per_e, int KT, int Kreal,
                                         int Nsrc, int Nval,
                                         const float* __restrict__ src,
                                         const float* __restrict__ sigma,
                                         __bf16* __restrict__ dst)
{
  int e = idx / per_e;
  int rem = idx - e * per_e;
  int g = rem >> 9;            // nt*KT + kt
  int nt = g / KT;
  int kt = g - nt * KT;
  int li = rem & 511;
  int lane = li >> 3, j = li & 7;
  int k = kt * 32 + (lane >> 4) * 8 + j;
  int n = nt * 16 + (lane & 15);
  float v = 0.f;
  if (k < Kreal && n < Nval) {
    v = src[(size_t)e * Kreal * Nsrc + (size_t)k * Nsrc + n];
    if (sigma) v *= 1.f / (sigma[k] + 1e-8f);   // fold input normalization
  }
  dst[idx] = (__bf16)v;
}

// Small matrices (W0 x2, W2 x2) + bias folds: gather path (cheap, cached).
__global__ void prep_small(const float* __restrict__ wl0, const float* __restrict__ wl2,
                           const float* __restrict__ wp0, const float* __restrict__ wp2,
                           const float* __restrict__ bl0, const float* __restrict__ bp0,
                           const float* __restrict__ mu_leg, const float* __restrict__ sigma_leg,
                           const float* __restrict__ mu_pose, const float* __restrict__ sigma_pose,
                           __bf16* __restrict__ WL0p, __bf16* __restrict__ WL2p,
                           __bf16* __restrict__ WP0p, __bf16* __restrict__ WP2p,
                           float* __restrict__ bl0f, float* __restrict__ bp0f)
{
  const int S0 = 65536, S2 = 32768;
  const int total = 2 * (S0 + S2) + 4096;
  for (int idx0 = blockIdx.x * blockDim.x + threadIdx.x; idx0 < total;
       idx0 += gridDim.x * blockDim.x) {
    int x = idx0;
    if (x < S0)              { pack_one(x, 16384, 1, 6, 512, 512, wl0, sigma_leg, WL0p); }
    else if ((x -= S0) < S2) { pack_one(x, 8192, 16, 512, 8, 8, wl2, nullptr, WL2p); }
    else if ((x -= S2) < S0) { pack_one(x, 16384, 1, 29, 512, 512, wp0, sigma_pose, WP0p); }
    else if ((x -= S0) < S2) { pack_one(x, 8192, 16, 512, 26, 16, wp2, nullptr, WP2p); }
    else {
      x -= S2;  // bias folds: b0' = b0 - sum_k mu[k]/(sigma[k]+eps) * W0[k,:]
      if (x < 2048) {
        int e = x >> 9, n = x & 511;
        float s = bl0[e * 512 + n];
        #pragma unroll
        for (int k = 0; k < 6; ++k)
          s -= mu_leg[k] / (sigma_leg[k] + 1e-8f) * wl0[(e * 6 + k) * 512 + n];
        bl0f[e * 512 + n] = s;
      } else {
        x -= 2048;
        int e = x >> 9, n = x & 511;
        float s = bp0[e * 512 + n];
        for (int k = 0; k < 29; ++k)
          s -= mu_pose[k] / (sigma_pose[k] + 1e-8f) * wp0[(e * 29 + k) * 512 + n];
        bp0f[e * 512 + n] = s;
      }
    }
  }
}

// W1 matrices (512x512): coalesced strip packer. Block = one (mat,e,nt)
// 512x16 column strip; stage f32->bf16 in LDS coalesced, emit contiguous.
__global__ __launch_bounds__(256) void prep_w1(const float* __restrict__ wl1,
                                               const float* __restrict__ wp1,
                                               __bf16* __restrict__ WL1p,
                                               __bf16* __restrict__ WP1p)
{
  __shared__ __bf16 st[512][20];
  const int b = blockIdx.x;          // 0..255: [mat(1) | e(2) | nt(5)]
  const float* src = (b & 128) ? wp1 : wl1;
  __bf16* dst = (b & 128) ? WP1p : WL1p;
  const int e = (b >> 5) & 3, nt = b & 31;
  src += (size_t)e * 262144 + nt * 16;
  dst += (size_t)e * 262144 + (size_t)nt * 8192;
  const int t = threadIdx.x;

  const int k0 = t >> 2, nq = t & 3;
  #pragma unroll
  for (int it = 0; it < 8; ++it) {
    int k = it * 64 + k0;
    f32x4 v = *(const f32x4*)(src + (size_t)k * 512 + nq * 4);
    #pragma unroll
    for (int j = 0; j < 4; ++j) st[k][nq * 4 + j] = (__bf16)v[j];
  }
  __syncthreads();
  #pragma unroll
  for (int it = 0; it < 4; ++it) {
    int lo = it * 256 + t;           // bf16x8 index 0..1023
    int kt = lo >> 6, lane = lo & 63;
    int kb = kt * 32 + (lane >> 4) * 8;
    int n = lane & 15;
    bf16x8 o;
    #pragma unroll
    for (int j = 0; j < 8; ++j) o[j] = st[kb + j][n];
    *(bf16x8*)(dst + (size_t)lo * 8) = o;
  }
}

// ---------------- fused model kernel (R0/R2 verbatim) -----------------------
__global__ __launch_bounds__(512) void fused_kernel(
    const float* __restrict__ state, const float* __restrict__ act,
    const float* __restrict__ bl1, const float* __restrict__ bl2,
    const float* __restrict__ bp1, const float* __restrict__ bp2,
    const float* __restrict__ mu_t_leg, const float* __restrict__ sigma_t_leg,
    const float* __restrict__ mu_t_pose, const float* __restrict__ sigma_t_pose,
    const __bf16* __restrict__ WL0p, const __bf16* __restrict__ WL1p,
    const __bf16* __restrict__ WL2p, const __bf16* __restrict__ WP0p,
    const __bf16* __restrict__ WP1p, const __bf16* __restrict__ WP2p,
    const float* __restrict__ bl0f, const float* __restrict__ bp0f,
    float* __restrict__ out)
{
  __shared__ alignas(16) __bf16 h1[128 * H1S];   // 133120 B
  __shared__ alignas(16) __bf16 h2c[64 * H2S];   // 17408 B (union with a0)
  __shared__ float ldiff[64][16];                // 4096 B
  __shared__ float legacc[64][16];               // 4096 B  -> total 158 KB
  __bf16* a0s = h2c;                             // a0 <=128*40=10240B, fits

  const int tid = threadIdx.x;
  const int wv = tid >> 6;        // wave 0..7
  const int lane = tid & 63;
  const int quad = lane >> 4;
  const int l16 = lane & 15;
  const int b0 = blockIdx.x * 64;

  for (int i = tid; i < 64 * 16; i += 512) ((float*)legacc)[i] = 0.f;
  f32x4 posacc = {0.f, 0.f, 0.f, 0.f};
  __syncthreads();

  for (int e = 0; e < E_; ++e) {
    const float* se = state + (size_t)e * B_ * 29;
    const float* ae = act + (size_t)e * B_ * 8;

    // ================= leg MLP: 2 passes of 128 leg rows =================
    for (int half = 0; half < 2; ++half) {
      __syncthreads();   // h2c/a0 region free (prior readers done)
      // ---- a0 build: 128 rows (ib*32+t) x 32 cols (6 real)
      for (int i = tid; i < 128 * 32; i += 512) {
        int r = i >> 5, c = i & 31;
        float v = 0.f;
        if (c < 6) {
          int ib = r >> 5;
          int b = b0 + half * 32 + (r & 31);
          const float* sp = se + (size_t)b * 29;
          if (c == 0) v = sp[13 + 2 * ib];
          else if (c == 1) v = sp[21 + 2 * ib];
          else if (c == 2) v = sp[14 + 2 * ib];
          else if (c == 3) v = sp[22 + 2 * ib];
          else if (c == 4) v = ae[(size_t)b * 8 + 2 * ib];
          else v = ae[(size_t)b * 8 + 2 * ib + 1];
        }
        a0s[r * A0S + c] = (__bf16)v;
      }
      __syncthreads();

      // ---- layer0: h1(128x512) = relu(A0 @ W0 + b0'); wave owns 4 col-tiles
      {
        const __bf16* W0 = WL0p + (size_t)e * 16384;
        const float* b0v = bl0f + e * 512;
        bf16x8 bfr[4]; float bs[4];
        #pragma unroll
        for (int i = 0; i < 4; ++i) {
          int ct = wv * 4 + i;
          bfr[i] = *(const bf16x8*)(W0 + ((size_t)ct * 64 + lane) * 8);
          bs[i] = b0v[ct * 16 + l16];
        }
        for (int rt = 0; rt < 8; ++rt) {
          bf16x8 afr = *(const bf16x8*)&a0s[(rt * 16 + l16) * A0S + quad * 8];
          #pragma unroll
          for (int i = 0; i < 4; ++i) {
            f32x4 acc = {bs[i], bs[i], bs[i], bs[i]};
            acc = mfma16(afr, bfr[i], acc);
            int col = (wv * 4 + i) * 16 + l16;
            #pragma unroll
            for (int r = 0; r < 4; ++r)
              h1[(rt * 16 + quad * 4 + r) * H1S + col] = (__bf16)fmaxf(acc[r], 0.f);
          }
        }
      }
      __syncthreads();

      // ---- layer1 (128x512x512) + fused layer2; wave tile 64r x 32c
      const __bf16* W1 = WL1p + (size_t)e * 262144;
      const __bf16* W2 = WL2p + (size_t)e * 8192;
      const float* b1v = bl1 + e * 512;
      const int rg = wv >> 2, cg = wv & 3;
      float bv2 = (l16 < 8) ? bl2[e * 8 + l16] : 0.f;
      f32x4 oacc = {bv2, bv2, bv2, bv2};     // wave wv owns row-tile wv (l2)

      for (int cc = 0; cc < 4; ++cc) {
        f32x4 acc[4][2];
        #pragma unroll
        for (int ct = 0; ct < 2; ++ct) {
          float bias = b1v[cc * 128 + cg * 32 + ct * 16 + l16];
          #pragma unroll
          for (int i = 0; i < 4; ++i) acc[i][ct] = (f32x4){bias, bias, bias, bias};
        }
        const __bf16* Wc = W1 + (size_t)(cc * 8 + cg * 2) * 8192;
        #pragma unroll 4
        for (int kt = 0; kt < 16; ++kt) {
          bf16x8 afr[4];
          #pragma unroll
          for (int i = 0; i < 4; ++i)
            afr[i] = *(const bf16x8*)&h1[(rg * 64 + i * 16 + l16) * H1S + kt * 32 + quad * 8];
          #pragma unroll
          for (int ct = 0; ct < 2; ++ct) {
            bf16x8 bfr = *(const bf16x8*)(Wc + (((size_t)ct * 16 + kt) * 64 + lane) * 8);
            #pragma unroll
            for (int i = 0; i < 4; ++i) acc[i][ct] = mfma16(afr[i], bfr, acc[i][ct]);
          }
        }
        // stage h2 in two 64-row halves; owners accumulate layer2
        #pragma unroll
        for (int hh = 0; hh < 2; ++hh) {
          __syncthreads();
          if (rg == hh) {
            #pragma unroll
            for (int i = 0; i < 4; ++i)
              #pragma unroll
              for (int ct = 0; ct < 2; ++ct)
                #pragma unroll
                for (int r = 0; r < 4; ++r)
                  h2c[(i * 16 + quad * 4 + r) * H2S + cg * 32 + ct * 16 + l16] =
                      (__bf16)fmaxf(acc[i][ct][r], 0.f);
          }
          __syncthreads();
          if ((wv >> 2) == hh) {
            #pragma unroll
            for (int k2 = 0; k2 < 4; ++k2) {
              bf16x8 afr2 = *(const bf16x8*)&h2c[((wv & 3) * 16 + l16) * H2S + k2 * 32 + quad * 8];
              bf16x8 bfr2 = *(const bf16x8*)(W2 + ((size_t)(cc * 4 + k2) * 64 + lane) * 8);
              oacc = mfma16(afr2, bfr2, oacc);
            }
          }
        }
      }
      // ---- leg epilogue: ldiff (only first 4 outputs used)
      if (l16 < 4) {
        float sc = sigma_t_leg[l16] + 1e-8f;
        float mv = mu_t_leg[l16];
        #pragma unroll
        for (int r = 0; r < 4; ++r) {
          int L = wv * 16 + quad * 4 + r;    // leg row = ib*32 + t
          ldiff[half * 32 + (L & 31)][(L >> 5) * 4 + l16] = oacc[r] * sc + mv;
        }
      }
    } // half

    // ================= pose MLP: 64 rows =================
    __syncthreads();   // ldiff ready, h2c free
    for (int i = tid; i < 64 * 32; i += 512) {
      int t = i >> 5, c = i & 31;
      float v = 0.f;
      if (c < 13) v = se[(size_t)(b0 + t) * 29 + c];
      else if (c < 29) { int ib, j; fmt_map(c - 13, ib, j); v = ldiff[t][ib * 4 + j]; }
      a0s[t * A0S + c] = (__bf16)v;
    }
    for (int i = tid; i < 64 * 16; i += 512) {   // legs output accumulation
      int t = i >> 4, k = i & 15;
      int ib, j; fmt_map(k, ib, j);
      legacc[t][k] += se[(size_t)(b0 + t) * 29 + 13 + k] + ldiff[t][ib * 4 + j];
    }
    __syncthreads();

    // ---- pose layer0: h1(64x512)
    {
      const __bf16* W0 = WP0p + (size_t)e * 16384;
      const float* b0v = bp0f + e * 512;
      bf16x8 bfr[4]; float bs[4];
      #pragma unroll
      for (int i = 0; i < 4; ++i) {
        int ct = wv * 4 + i;
        bfr[i] = *(const bf16x8*)(W0 + ((size_t)ct * 64 + lane) * 8);
        bs[i] = b0v[ct * 16 + l16];
      }
      for (int rt = 0; rt < 4; ++rt) {
        bf16x8 afr = *(const bf16x8*)&a0s[(rt * 16 + l16) * A0S + quad * 8];
        #pragma unroll
        for (int i = 0; i < 4; ++i) {
          f32x4 acc = {bs[i], bs[i], bs[i], bs[i]};
          acc = mfma16(afr, bfr[i], acc);
          int col = (wv * 4 + i) * 16 + l16;
          #pragma unroll
          for (int r = 0; r < 4; ++r)
            h1[(rt * 16 + quad * 4 + r) * H1S + col] = (__bf16)fmaxf(acc[r], 0.f);
        }
      }
    }
    __syncthreads();

    // ---- pose layer1 (64x512x512) + fused layer2 (N=13 -> 1 col-tile)
    {
      const __bf16* W1 = WP1p + (size_t)e * 262144;
      const __bf16* W2 = WP2p + (size_t)e * 8192;
      const float* b1v = bp1 + e * 512;
      float bvp = bp2[e * 26 + l16];
      f32x4 po = {bvp, bvp, bvp, bvp};       // waves 0..3 own row-tiles 0..3

      for (int cc2 = 0; cc2 < 2; ++cc2) {
        f32x4 acc[4][2];
        #pragma unroll
        for (int ct = 0; ct < 2; ++ct) {
          float bias = b1v[cc2 * 256 + wv * 32 + ct * 16 + l16];
          #pragma unroll
          for (int i = 0; i < 4; ++i) acc[i][ct] = (f32x4){bias, bias, bias, bias};
        }
        const __bf16* Wc = W1 + (size_t)(cc2 * 16 + wv * 2) * 8192;
        #pragma unroll 4
        for (int kt = 0; kt < 16; ++kt) {
          bf16x8 afr[4];
          #pragma unroll
          for (int i = 0; i < 4; ++i)
            afr[i] = *(const bf16x8*)&h1[(i * 16 + l16) * H1S + kt * 32 + quad * 8];
          #pragma unroll
          for (int ct = 0; ct < 2; ++ct) {
            bf16x8 bfr = *(const bf16x8*)(Wc + (((size_t)ct * 16 + kt) * 64 + lane) * 8);
            #pragma unroll
            for (int i = 0; i < 4; ++i) acc[i][ct] = mfma16(afr[i], bfr, acc[i][ct]);
          }
        }
        // stage in two 128-col halves (cols cg<4 then cg>=4)
        #pragma unroll
        for (int hh = 0; hh < 2; ++hh) {
          __syncthreads();
          if ((wv >> 2) == hh) {
            int cgl = wv & 3;
            #pragma unroll
            for (int i = 0; i < 4; ++i)
              #pragma unroll
              for (int ct = 0; ct < 2; ++ct)
                #pragma unroll
                for (int r = 0; r < 4; ++r)
                  h2c[(i * 16 + quad * 4 + r) * H2S + cgl * 32 + ct * 16 + l16] =
                      (__bf16)fmaxf(acc[i][ct][r], 0.f);
          }
          __syncthreads();
          if (wv < 4) {
            #pragma unroll
            for (int k2 = 0; k2 < 4; ++k2) {
              bf16x8 afr2 = *(const bf16x8*)&h2c[(wv * 16 + l16) * H2S + k2 * 32 + quad * 8];
              bf16x8 bfr2 = *(const bf16x8*)(W2 + ((size_t)(cc2 * 8 + hh * 4 + k2) * 64 + lane) * 8);
              po = mfma16(afr2, bfr2, po);
            }
          }
        }
      }
      // pose epilogue: accumulate into registers across ensembles
      if (wv < 4 && l16 < 13) {
        float sc = sigma_t_pose[l16] + 1e-8f;
        float mv = mu_t_pose[l16];
        #pragma unroll
        for (int r = 0; r < 4; ++r) {
          int row = wv * 16 + quad * 4 + r;
          posacc[r] += po[r] * sc + mv + se[(size_t)(b0 + row) * 29 + l16];
        }
      }
    }
  } // e

  // ================= final writes: mean over ensembles =================
  if (wv < 4 && l16 < 13) {
    #pragma unroll
    for (int r = 0; r < 4; ++r) {
      int row = wv * 16 + quad * 4 + r;
      out[(size_t)(b0 + row) * 29 + l16] = 0.25f * posacc[r];
    }
  }
  for (int i = tid; i < 64 * 16; i += 512) {
    int t = i >> 4, k = i & 15;
    out[(size_t)(b0 + t) * 29 + 13 + k] = 0.25f * legacc[t][k];
  }
}

// ---------------- launch ----------------------------------------------------
extern "C" void kernel_launch(void* const* d_in, const int* in_sizes, int n_in,
                              void* d_out, int out_size, void* d_ws, size_t ws_size,
                              hipStream_t stream) {
  const float* state = (const float*)d_in[0];
  const float* act = (const float*)d_in[1];
  const float* wl0 = (const float*)d_in[2];
  const float* bl0 = (const float*)d_in[3];
  const float* wl1 = (const float*)d_in[4];
  const float* bl1 = (const float*)d_in[5];
  const float* wl2 = (const float*)d_in[6];
  const float* bl2 = (const float*)d_in[7];
  const float* wp0 = (const float*)d_in[8];
  const float* bp0 = (const float*)d_in[9];
  const float* wp1 = (const float*)d_in[10];
  const float* bp1 = (const float*)d_in[11];
  const float* wp2 = (const float*)d_in[12];
  const float* bp2 = (const float*)d_in[13];
  const float* mu_leg = (const float*)d_in[14];
  const float* sigma_leg = (const float*)d_in[15];
  const float* mu_pose = (const float*)d_in[16];
  const float* sigma_pose = (const float*)d_in[17];
  const float* mu_t_leg = (const float*)d_in[18];
  const float* sigma_t_leg = (const float*)d_in[19];
  const float* mu_t_pose = (const float*)d_in[20];
  const float* sigma_t_pose = (const float*)d_in[21];
  float* out = (float*)d_out;

  char* ws = (char*)d_ws;
  __bf16* WL0p = (__bf16*)(ws);
  __bf16* WL1p = (__bf16*)(ws + 131072);
  __bf16* WL2p = (__bf16*)(ws + 2228224);
  __bf16* WP0p = (__bf16*)(ws + 2293760);
  __bf16* WP1p = (__bf16*)(ws + 2424832);
  __bf16* WP2p = (__bf16*)(ws + 4521984);
  float* bl0f = (float*)(ws + 4587520);
  float* bp0f = (float*)(ws + 4595712);

  prep_small<<<256, 256, 0, stream>>>(wl0, wl2, wp0, wp2, bl0, bp0,
                                      mu_leg, sigma_leg, mu_pose, sigma_pose,
                                      WL0p, WL2p, WP0p, WP2p, bl0f, bp0f);
  prep_w1<<<256, 256, 0, stream>>>(wl1, wp1, WL1p, WP1p);
  fused_kernel<<<256, 512, 0, stream>>>(state, act, bl1, bl2, bp1, bp2,
                                        mu_t_leg, sigma_t_leg, mu_t_pose, sigma_t_pose,
                                        WL0p, WL1p, WL2p, WP0p, WP1p, WP2p,
                                        bl0f, bp0f, out);
}